// Round 11
// baseline (579.766 us; speedup 1.0000x reference)
//
#include <hip/hip_runtime.h>
#include <hip/hip_bf16.h>

// Problem dims
#define B_ 1024
#define I_ 512
#define O_ 512
#define M_ 8
#define R_ 512
#define A_ 16
#define D_ 128   // M_*A_
#define NLEV 10  // squaring levels; rho via (L10-2L9+L8)/256 (Richardson)

using bf16 = __hip_bfloat16;
typedef __attribute__((ext_vector_type(8))) short bf16x8;
typedef __attribute__((ext_vector_type(4))) float f32x4;

__device__ __forceinline__ short f2b(float x){
  __hip_bfloat16 h = __float2bfloat16(x);
  union { __hip_bfloat16 h; short s; } u; u.h = h; return u.s;
}
__device__ __forceinline__ float s2f(short s){
  union { short s[2]; float f; } u; u.s[0] = 0; u.s[1] = s; return u.f;
}
__device__ __forceinline__ float fast_tanh(float x){
  float xx = fminf(fmaxf(x, -9.5f), 9.5f);
  float e2 = __expf(2.f * xx);
  return (e2 - 1.f) / (e2 + 1.f);
}

// Frag-packed layout: matrix [Rows][K] bf16, element (r,k) at
// (r>>4)*(16*K) + (k>>3)*128 + (r&15)*8 + (k&7): fragment load = 1KB burst.
#define PK(r, k, K) (((size_t)((r) >> 4)) * (16 * (K)) + (((k) >> 3) * 128) + (((r) & 15) * 8) + ((k) & 7))

// Blocked-swizzled tile layout for the eigen chain: per unit, 8x8 tiles of
// 64x64 bf16; tile (rt,ct) at (rt*8+ct)*4096 shorts; element (r,c) at
// swz_idx(r,c). gl_lds staging is linear; reads apply the XOR.
__device__ __forceinline__ int swz_idx(int r, int c){
  return r * 64 + (((c >> 3) ^ (r & 7)) << 3) + (c & 7);
}

__device__ __forceinline__ void gl_lds16(const short* g, short* l){
  __builtin_amdgcn_global_load_lds((const __attribute__((address_space(1))) void*)g,
                                   (__attribute__((address_space(3))) void*)l, 16, 0, 0);
}

template<int N> __device__ __forceinline__ void wait_vmcnt(){
  if constexpr (N == 0)      asm volatile("s_waitcnt vmcnt(0)" ::: "memory");
  else if constexpr (N == 4) asm volatile("s_waitcnt vmcnt(4)" ::: "memory");
  else                       asm volatile("s_waitcnt vmcnt(8)" ::: "memory");
}

// ---------------------------------------------------------------------------
// 64x64 inner loop, depth-4 named-register pipeline. Separate A/B k-strides
// (A may be packed/LDS, B row-major global).
// ---------------------------------------------------------------------------
__device__ __forceinline__ void mm64_d4(const short* __restrict__ A0, const short* __restrict__ B0,
                                        int rOffA, int rOffB, int kStrideA, int kStrideB, int kiters,
                                        f32x4 (&acc)[2][2]){
  const short* A1 = A0 + rOffA;
  const short* B1 = B0 + rOffB;
  bf16x8 a0, a1, b0, b1, c0, c1, d0, d1, e0, e1, f0, f1, g0, g1, h0, h1;
  a0 = *(const bf16x8*)(A0); a1 = *(const bf16x8*)(A1);
  b0 = *(const bf16x8*)(B0); b1 = *(const bf16x8*)(B1);
  if (kiters > 1){
    c0 = *(const bf16x8*)(A0 + kStrideA); c1 = *(const bf16x8*)(A1 + kStrideA);
    d0 = *(const bf16x8*)(B0 + kStrideB); d1 = *(const bf16x8*)(B1 + kStrideB);
  }
  if (kiters > 2){
    e0 = *(const bf16x8*)(A0 + 2 * kStrideA); e1 = *(const bf16x8*)(A1 + 2 * kStrideA);
    f0 = *(const bf16x8*)(B0 + 2 * kStrideB); f1 = *(const bf16x8*)(B1 + 2 * kStrideB);
  }
  if (kiters > 3){
    g0 = *(const bf16x8*)(A0 + 3 * kStrideA); g1 = *(const bf16x8*)(A1 + 3 * kStrideA);
    h0 = *(const bf16x8*)(B0 + 3 * kStrideB); h1 = *(const bf16x8*)(B1 + 3 * kStrideB);
  }
  for (int kk = 0; kk < kiters; ++kk){
    bf16x8 n0, n1, m0, m1;
    if (kk + 4 < kiters){
      n0 = *(const bf16x8*)(A0 + (size_t)(kk + 4) * kStrideA);
      n1 = *(const bf16x8*)(A1 + (size_t)(kk + 4) * kStrideA);
      m0 = *(const bf16x8*)(B0 + (size_t)(kk + 4) * kStrideB);
      m1 = *(const bf16x8*)(B1 + (size_t)(kk + 4) * kStrideB);
    }
    acc[0][0] = __builtin_amdgcn_mfma_f32_16x16x32_bf16(a0, b0, acc[0][0], 0, 0, 0);
    acc[0][1] = __builtin_amdgcn_mfma_f32_16x16x32_bf16(a0, b1, acc[0][1], 0, 0, 0);
    acc[1][0] = __builtin_amdgcn_mfma_f32_16x16x32_bf16(a1, b0, acc[1][0], 0, 0, 0);
    acc[1][1] = __builtin_amdgcn_mfma_f32_16x16x32_bf16(a1, b1, acc[1][1], 0, 0, 0);
    a0 = c0; a1 = c1; b0 = d0; b1 = d1;
    c0 = e0; c1 = e1; d0 = f0; d1 = f1;
    e0 = g0; e1 = g1; f0 = h0; f1 = h1;
    g0 = n0; g1 = n1; h0 = m0; h1 = m1;
  }
}

// ---------------------------------------------------------------------------
// Merged prep kernel: ALL independent converts incl. W-prep.
//   bid 0..511     : zero outYi (bid 0 also zeros norm2 block)
//   bid 512..2815  : cvt (Si->SiB row-major + SiBuP packed ; Xi->XiB)
//   bid 2816..2839 : Wq/Wk/Wv transpose
//   bid 2840..2967 : Win transpose -> WinTP packed
//   bid 2968..3479 : Wout transpose
//   bid 3480..3991 : W -> X0 (blocked-swz) + WTpP packed + norm2tmp[u*64+tile]
// ---------------------------------------------------------------------------
__global__ __launch_bounds__(256) void k_prep_all(
    const float* __restrict__ Si, const float* __restrict__ Xi,
    const float* __restrict__ Wq, const float* __restrict__ Wk, const float* __restrict__ Wv,
    const float* __restrict__ Win, const float* __restrict__ Wout, const float* __restrict__ W,
    short* __restrict__ SiB, short* __restrict__ SiBuP, short* __restrict__ XiB,
    short* __restrict__ WqT, short* __restrict__ WkT, short* __restrict__ WvT,
    short* __restrict__ WinTP, short* __restrict__ WoutT,
    short* __restrict__ X, short* __restrict__ WTpP,
    float* __restrict__ outYi, float* __restrict__ norm2, float* __restrict__ norm2tmp){
  __shared__ short sh[16 * 520];
  const int bid = blockIdx.x, t = threadIdx.x;
  if (bid < 512){
    if (bid == 0){ for (int i = t; i < 136; i += 256) norm2[i] = 0.f; }
    #pragma unroll
    for (int e = 0; e < 4; ++e) outYi[bid * 1024 + e * 256 + t] = 0.f;
  } else if (bid < 2816){
    const int bb0 = bid - 512;
    #pragma unroll
    for (int e = 0; e < 8; ++e){
      int idx = bb0 * 2048 + e * 256 + t;
      if (idx < 4194304){
        short b = f2b(Si[idx]);
        SiB[idx] = b;
        int bb = idx >> 12, mm = (idx >> 9) & 7, cc = idx & 511;
        SiBuP[((size_t)mm << 19) + PK(bb, cc, 512)] = b;
      } else XiB[idx - 4194304] = f2b(Xi[idx - 4194304]);
    }
  } else if (bid < 2840){
    const int i = bid - 2816, which = i / 8, m = i % 8;
    const float* src = (which == 0) ? Wq : (which == 1) ? Wk : Wv;
    short* dst = (which == 0) ? WqT : (which == 1) ? WkT : WvT;
    src += (size_t)m * 8192; dst += (size_t)m * 8192;
    #pragma unroll
    for (int l = 0; l < 32; ++l){
      int idx = l * 256 + t, ii = idx >> 4, a = idx & 15;
      sh[a * 520 + ii] = f2b(src[idx]);
    }
    __syncthreads();
    #pragma unroll
    for (int l = 0; l < 32; ++l){
      int idx = l * 256 + t, a = idx >> 9, ii = idx & 511;
      dst[a * 512 + ii] = sh[a * 520 + ii];
    }
  } else if (bid < 2968){
    // Win [m][128][512] fp32 -> WinTP packed [m]{rows=512(R), K=128(D)}
    const int i = bid - 2840;
    const int x = i & 7, y = (i >> 3) & 1, z = i >> 4;
    const float* src = Win + (size_t)z * 65536;
    const int c0 = x * 64, r0 = y * 64;
    #pragma unroll
    for (int l = 0; l < 16; ++l){
      int idx = l * 256 + t, r = idx >> 6, c = idx & 63;
      sh[r * 66 + c] = f2b(src[(size_t)(r0 + r) * 512 + c0 + c]);
    }
    __syncthreads();
    #pragma unroll
    for (int l = 0; l < 16; ++l){
      int idx = l * 256 + t, r = idx >> 6, c = idx & 63;
      int R2 = c0 + r, K2 = r0 + c;
      WinTP[(size_t)z * 65536 + PK(R2, K2, 128)] = sh[c * 66 + r];
    }
  } else if (bid < 3480){
    const int i = bid - 2968;
    const int x = i & 7, y = i >> 3;
    const int c0 = x * 64, r0 = y * 64;
    #pragma unroll
    for (int l = 0; l < 16; ++l){
      int idx = l * 256 + t, r = idx >> 6, c = idx & 63;
      sh[r * 66 + c] = f2b(Wout[(size_t)(r0 + r) * 512 + c0 + c]);
    }
    __syncthreads();
    #pragma unroll
    for (int l = 0; l < 16; ++l){
      int idx = l * 256 + t, r = idx >> 6, c = idx & 63;
      WoutT[(size_t)(c0 + r) * 4096 + r0 + c] = sh[c * 66 + r];
    }
  } else {
    // W-prep: X0 blocked-swz + WTpP packed + norm2tmp partial
    const int i = bid - 3480, u = i >> 6, tile = i & 63;
    const int rt = tile >> 3, ct = tile & 7;
    const int row0 = rt * 64, col0 = ct * 64;
    const size_t off = (size_t)u * (R_ * R_);
    const size_t tXo = off + (size_t)(rt * 8 + ct) * 4096;
    const int lane = t & 63, wvv = t >> 6;
    float ss = 0.f;
    #pragma unroll
    for (int l = 0; l < 16; ++l){
      int idx = l * 256 + t, r = idx >> 6, c = idx & 63;
      short b = f2b(W[off + (size_t)(row0 + r) * R_ + col0 + c]);
      float vb = s2f(b);
      ss = fmaf(vb, vb, ss);
      X[tXo + swz_idx(r, c)] = b;
      sh[r * 66 + c] = b;
    }
    __syncthreads();
    #pragma unroll
    for (int l = 0; l < 16; ++l){
      int idx = l * 256 + t, r = idx >> 6, c = idx & 63;
      int R2 = col0 + r, K2 = row0 + c;
      WTpP[off + PK(R2, K2, 512)] = sh[c * 66 + r];
    }
    #pragma unroll
    for (int o = 32; o > 0; o >>= 1) ss += __shfl_xor(ss, o, 64);
    __syncthreads();
    float* rf = (float*)sh;
    if (lane == 0) rf[wvv] = ss;
    __syncthreads();
    if (t == 0) norm2tmp[u * 64 + tile] = rf[0] + rf[1] + rf[2] + rf[3];
  }
}

// ---------------------------------------------------------------------------
// Chain level + piggybacked main-pipeline work.
//   yy < 32            : chain — TWO 64x64 tiles per block (yy, yy+32)
//   yy >= 32, lev 1..4 : qkv piggyback (e in [0,136))
//   yy >= 32, lev 5..6 : attn piggyback (e in [0,1024))
//   yy >= 32, lev 7..10: pre-GEMM piggyback (accA/accB -> pA/pB; sscal-free)
// ---------------------------------------------------------------------------
__global__ __launch_bounds__(256, 3) void k_lev(
    const short* __restrict__ Xr, short* __restrict__ Xw,
    float* __restrict__ norm2, const float* __restrict__ norm2tmp, const int lev,
    const short* __restrict__ SiB, const short* __restrict__ XiB,
    const short* __restrict__ WqT, const short* __restrict__ WkT, const short* __restrict__ WvT,
    float* __restrict__ Kb, float* __restrict__ Vb, float* __restrict__ Qb,
    short* __restrict__ UiBuP,
    const short* __restrict__ SiBuP, const short* __restrict__ WinTP, const short* __restrict__ WTpP,
    float* __restrict__ pA, float* __restrict__ pB){
  __shared__ __align__(16) short SA[3][4096];
  __shared__ __align__(16) short SB[3][4096];
  const int u = blockIdx.x, yy = blockIdx.y;
  const int t = threadIdx.x, wv = t >> 6, lane = t & 63;
  const int wr = (wv >> 1) * 32, wc = (wv & 1) * 32;
  const int fm = lane & 15, fq = lane >> 4;

  if (yy >= 32){
    const int e = (yy - 32) * 8 + u;
    if (lev <= 4){
      // ---- qkv piggyback ----
      int z, x, yq;
      if (e < 64)       { z = 0; x = e & 1;         yq = (e >> 1)         + (lev - 1) * 32; }
      else if (e < 128) { z = 1; x = (e - 64) & 1;  yq = ((e - 64) >> 1)  + (lev - 1) * 32; }
      else              { z = 2; x = (e - 128) & 1; yq = ((e - 128) >> 1) + (lev - 1) * 4;  }
      const int ko = fq * 8;
      const int row0 = yq * 64, col0 = x * 64;
      const short* Abase = (z == 2) ? XiB : SiB;
      const short* Bbase = (z == 0) ? WkT : (z == 1) ? WvT : WqT;
      const short* A0 = Abase + (size_t)(row0 + wr + fm) * 512 + ko;
      const short* B0 = Bbase + (size_t)(col0 + wc + fm) * 512 + ko;
      f32x4 zz = {0.f, 0.f, 0.f, 0.f};
      f32x4 acc[2][2] = {{zz, zz}, {zz, zz}};
      mm64_d4(A0, B0, 16 * 512, 16 * 512, 32, 32, 16, acc);
      float* dst = (z == 0) ? Kb : (z == 1) ? Vb : Qb;
      #pragma unroll
      for (int i = 0; i < 2; ++i)
        #pragma unroll
        for (int j = 0; j < 2; ++j)
          #pragma unroll
          for (int r = 0; r < 4; ++r){
            int row = row0 + wr + i * 16 + fq * 4 + r;
            int col = col0 + wc + j * 16 + fm;
            float v = acc[i][j][r];
            if (z == 2) dst[row * 128 + col] = v;
            else {
              int b = row >> 3, n = row & 7, mc = col >> 4, a = col & 15;
              dst[b * 1024 + mc * 128 + n * 16 + a] = v;
            }
          }
    } else if (lev <= 6){
      // ---- attn piggyback (one wave per (b,m)) ----
      float* fsh = (float*)&SA[0][0];
      float* sQ = fsh, *sK = fsh + 512, *sV = fsh + 1024, *sAa = fsh + 1536;
      const int wib = wv;
      const int w = (e + (lev - 5) * 1024) * 4 + wib;
      const int b = w >> 3, m = w & 7;
      for (int e2 = lane; e2 < 128; e2 += 64){
        sQ[wib * 128 + e2] = Qb[b * 128 + e2];
        sK[wib * 128 + e2] = Kb[b * 1024 + m * 128 + e2];
        sV[wib * 128 + e2] = Vb[b * 1024 + m * 128 + e2];
      }
      __syncthreads();
      const int q = lane >> 3, n = lane & 7;
      float s = 0.f;
      #pragma unroll
      for (int a = 0; a < 16; ++a) s = fmaf(sQ[wib * 128 + q * 16 + a], sK[wib * 128 + n * 16 + a], s);
      float mx = s;
      for (int d2 = 1; d2 < 8; d2 <<= 1) mx = fmaxf(mx, __shfl_xor(mx, d2, 64));
      float p = __expf(s - mx);
      float sm = p;
      for (int d2 = 1; d2 < 8; d2 <<= 1) sm += __shfl_xor(sm, d2, 64);
      float ai = p / (sm * 11.313708498984761f);   // softmax then /sqrt(128)
      sAa[wib * 64 + q * 8 + n] = ai;
      __syncthreads();
      for (int e2 = lane; e2 < 128; e2 += 64){
        int q2 = e2 >> 4, a2 = e2 & 15;
        float acc = 0.f;
        #pragma unroll
        for (int n2 = 0; n2 < 8; ++n2) acc = fmaf(sAa[wib * 64 + q2 * 8 + n2], sV[wib * 128 + n2 * 16 + a2], acc);
        UiBuP[(size_t)m * 131072 + PK(b, e2, 128)] = f2b(acc);
      }
    } else {
      // ---- pre-GEMM piggyback: job j of 1024 over levels 7..10 (256/level) ----
      const int j = (lev - 7) * 256 + e;
      if (j >= 1024) return;
      const int m = j & 7, bz = (j >> 3) & 7, by = j >> 6;
      const int row0 = by * 64, col0 = bz * 64;
      const int lo = fm * 8 + fq * 128;
      f32x4 zz = {0.f, 0.f, 0.f, 0.f};
      f32x4 accA[2][2] = {{zz, zz}, {zz, zz}};
      f32x4 accB[2][2] = {{zz, zz}, {zz, zz}};
      {
        const short* A0 = UiBuP + (size_t)m * 131072 + (size_t)(row0 + wr) * 128 + lo;
        const short* B0 = WinTP + (size_t)m * 65536  + (size_t)(col0 + wc) * 128 + lo;
        mm64_d4(A0, B0, 16 * 128, 16 * 128, 512, 512, 4, accA);
      }
      {
        const short* A0 = SiBuP + (size_t)m * 524288 + (size_t)(row0 + wr) * 512 + lo;
        const short* B0 = WTpP  + (size_t)m * 262144 + (size_t)(col0 + wc) * 512 + lo;
        mm64_d4(A0, B0, 16 * 512, 16 * 512, 512, 512, 16, accB);
      }
      #pragma unroll
      for (int i = 0; i < 2; ++i)
        #pragma unroll
        for (int j2 = 0; j2 < 2; ++j2)
          #pragma unroll
          for (int r = 0; r < 4; ++r){
            int b = row0 + wr + i * 16 + fq * 4 + r;
            int c = col0 + wc + j2 * 16 + fm;
            size_t g = ((size_t)b * 8 + m) * 512 + c;
            pA[g] = accA[i][j2][r];
            pB[g] = accB[i][j2][r];
          }
    }
    return;
  }

  // ---- chain: two tiles per block (yy, yy+32) ----
  const size_t off = (size_t)u * (R_ * R_);
  const int swz = (fm & 7) << 4;
  int aof[2][2];
  #pragma unroll
  for (int i = 0; i < 2; ++i)
    #pragma unroll
    for (int kk = 0; kk < 2; ++kk)
      aof[i][kk] = (((wr + fm + i * 16) * 128 + kk * 64 + fq * 16) ^ swz);
  const int c0c = wc + fm,      c0h = c0c >> 3, c0l = c0c & 7;
  const int c1c = wc + 16 + fm, c1h = c1c >> 3, c1l = c1c & 7;
  float n2;
  if (lev == 1){
    n2 = 0.f;
    for (int i = 0; i < 64; ++i) n2 += norm2tmp[u * 64 + i];
  } else {
    n2 = norm2[(lev - 1) * 8 + u];
  }
  const float s2 = 1.f / n2;

  #pragma unroll 1
  for (int half = 0; half < 2; ++half){
    const int tile = yy + half * 32;
    const int rt = tile >> 3, ct = tile & 7;
    const size_t tXo = off + (size_t)(rt * 8 + ct) * 4096;
    const short* gA = Xr + off + (size_t)(rt * 8) * 4096 + t * 8;  // A tiles (rt,kt): +4096/kt
    const short* gB = Xr + off + (size_t)ct * 4096 + t * 8;        // B tiles (kt,ct): +32768/kt

    __syncthreads();   // protect LDS reuse across halves
    // prologue: stage tiles 0,1
    #pragma unroll
    for (int p = 0; p < 2; ++p){
      short* dA = &SA[p][0] + wv * 512;
      short* dB = &SB[p][0] + wv * 512;
      gl_lds16(gA + (size_t)p * 4096,         dA);
      gl_lds16(gA + (size_t)p * 4096 + 2048,  dA + 2048);
      gl_lds16(gB + (size_t)p * 32768,        dB);
      gl_lds16(gB + (size_t)p * 32768 + 2048, dB + 2048);
    }
    f32x4 zz = {0.f, 0.f, 0.f, 0.f};
    f32x4 acc[2][2] = {{zz, zz}, {zz, zz}};
    #pragma unroll
    for (int kt = 0; kt < 8; ++kt){
      if (kt < 7) wait_vmcnt<4>();
      else        wait_vmcnt<0>();
      __builtin_amdgcn_s_barrier();
      if (kt < 6){
        const int b = (kt + 2) % 3;
        short* dA = &SA[b][0] + wv * 512;
        short* dB = &SB[b][0] + wv * 512;
        gl_lds16(gA + (size_t)(kt + 2) * 4096,         dA);
        gl_lds16(gA + (size_t)(kt + 2) * 4096 + 2048,  dA + 2048);
        gl_lds16(gB + (size_t)(kt + 2) * 32768,        dB);
        gl_lds16(gB + (size_t)(kt + 2) * 32768 + 2048, dB + 2048);
      }
      const char*  Ab = (const char*)&SA[kt % 3][0];
      const short* Bb = &SB[kt % 3][0];
      #pragma unroll
      for (int kk = 0; kk < 2; ++kk){
        bf16x8 a0 = *(const bf16x8*)(Ab + aof[0][kk]);
        bf16x8 a1 = *(const bf16x8*)(Ab + aof[1][kk]);
        bf16x8 b0, b1;
        #pragma unroll
        for (int e = 0; e < 8; ++e){
          int rb = (kk * 32 + fq * 8 + e) * 64;
          b0[e] = Bb[rb + ((c0h ^ e) << 3) + c0l];
          b1[e] = Bb[rb + ((c1h ^ e) << 3) + c1l];
        }
        acc[0][0] = __builtin_amdgcn_mfma_f32_16x16x32_bf16(a0, b0, acc[0][0], 0, 0, 0);
        acc[0][1] = __builtin_amdgcn_mfma_f32_16x16x32_bf16(a0, b1, acc[0][1], 0, 0, 0);
        acc[1][0] = __builtin_amdgcn_mfma_f32_16x16x32_bf16(a1, b0, acc[1][0], 0, 0, 0);
        acc[1][1] = __builtin_amdgcn_mfma_f32_16x16x32_bf16(a1, b1, acc[1][1], 0, 0, 0);
      }
    }
    // epilogue: swizzled X' image in SA[0], linear full-line stores
    float ss = 0.f;
    #pragma unroll
    for (int i = 0; i < 2; ++i)
      #pragma unroll
      for (int j = 0; j < 2; ++j)
        #pragma unroll
        for (int r = 0; r < 4; ++r){
          int lr = wr + i * 16 + fq * 4 + r, lc = wc + j * 16 + fm;
          short b = f2b(acc[i][j][r] * s2);
          float vb = s2f(b);
          ss = fmaf(vb, vb, ss);
          SA[0][swz_idx(lr, lc)] = b;
        }
    __syncthreads();
    *(bf16x8*)(Xw + tXo + t * 8)        = *(const bf16x8*)(&SA[0][t * 8]);
    *(bf16x8*)(Xw + tXo + 2048 + t * 8) = *(const bf16x8*)(&SA[0][2048 + t * 8]);
    #pragma unroll
    for (int o = 32; o > 0; o >>= 1) ss += __shfl_xor(ss, o, 64);
    if (lane == 0) atomicAdd(&norm2[lev * 8 + u], ss);
  }
}

// ---------------------------------------------------------------------------
// Merged finalize + Yi GEMM. Grid (kslab=4, rowblk=16, colblk=8): linear =
// kslab + 4*row + 64*col -> the 8 redundant col-blocks (same slice) land on
// ONE XCD (stride 64 ≡ 0 mod 8) so pA/pB/Si reads are L2-shared.
// Per block: for each of 2 units in its K-slab, compute rho inline, build the
// 64x512 Snew bf16 slice in packed LDS (cb==0 writes outSnew), then MFMA
// A(LDS) x WoutT(global) accumulating across both halves; atomicAdd outYi.
// SnewB is never materialized in global memory.
// ---------------------------------------------------------------------------
__global__ __launch_bounds__(256, 2) void k_yi2(
    const float* __restrict__ pA, const float* __restrict__ pB,
    const float* __restrict__ norm2, const float* __restrict__ norm2tmp,
    const float* __restrict__ sr, const float* __restrict__ bias,
    const float* __restrict__ lr, const float* __restrict__ Si,
    const short* __restrict__ WoutT,
    float* __restrict__ outSnew, float* __restrict__ outYi){
  __shared__ __align__(16) short ssh[32768];   // 64 KB packed A-slice
  const int kslab = blockIdx.x, by = blockIdx.y, cb = blockIdx.z;
  const int t = threadIdx.x, wv = t >> 6, lane = t & 63;
  const int wr = (wv >> 1) * 32, wc = (wv & 1) * 32;
  const int fm = lane & 15, fq = lane >> 4;
  const int row0 = by * 64, col0 = cb * 64;
  const int lo = fm * 8 + fq * 128;
  f32x4 zz = {0.f, 0.f, 0.f, 0.f};
  f32x4 acc[2][2] = {{zz, zz}, {zz, zz}};
  #pragma unroll 1
  for (int half = 0; half < 2; ++half){
    const int m = kslab * 2 + half;
    // inline rho for unit m
    float n0 = 0.f;
    for (int i = 0; i < 64; ++i) n0 += norm2tmp[m * 64 + i];
    float L = 0.5f * logf(n0), L8 = 0.f, L9 = 0.f, L10 = 0.f;
    for (int j = 1; j <= NLEV; ++j){
      L = 2.f * L + 0.5f * logf(norm2[j * 8 + m]);
      if (j == NLEV - 2) L8  = L;
      if (j == NLEV - 1) L9  = L;
      if (j == NLEV)     L10 = L;
    }
    const float sc = sr[m] / expf((L10 - 2.f * L9 + L8) * (1.f / 256.f));
    const float lm = lr[m];
    __syncthreads();   // prior half's LDS reads complete before overwrite
    #pragma unroll 4
    for (int l = 0; l < 128; ++l){
      int idx = l * 256 + t, r = idx >> 9, c = idx & 511;
      size_t g = (size_t)(row0 + r) * 4096 + m * 512 + c;
      float pre = pA[g] + sc * pB[g] + bias[m * 512 + c];
      float sn = (1.f - lm) * Si[g] + lm * fast_tanh(pre);
      if (cb == 0) outSnew[g] = sn;
      ssh[PK(r, c, 512)] = f2b(sn);
    }
    __syncthreads();
    const short* A0 = ssh + wr * 512 + lo;
    const short* B0 = WoutT + (size_t)(col0 + wc + fm) * 4096 + kslab * 1024 + half * 512 + fq * 8;
    mm64_d4(A0, B0, 16 * 512, 16 * 4096, 512, 32, 16, acc);
  }
  #pragma unroll
  for (int i = 0; i < 2; ++i)
    #pragma unroll
    for (int j = 0; j < 2; ++j)
      #pragma unroll
      for (int r = 0; r < 4; ++r){
        int row = row0 + wr + i * 16 + fq * 4 + r;
        int col = col0 + wc + j * 16 + fm;
        atomicAdd(&outYi[row * 512 + col], acc[i][j][r]);
      }
}

// ---------------------------------------------------------------------------
extern "C" void kernel_launch(void* const* d_in, const int* in_sizes, int n_in,
                              void* d_out, int out_size, void* d_ws, size_t ws_size,
                              hipStream_t stream) {
  const float* Xi   = (const float*)d_in[0];
  const float* Si   = (const float*)d_in[1];
  const float* Wq   = (const float*)d_in[2];
  const float* Wk   = (const float*)d_in[3];
  const float* Wv   = (const float*)d_in[4];
  const float* Wout = (const float*)d_in[5];
  const float* W    = (const float*)d_in[6];
  const float* Win  = (const float*)d_in[7];
  const float* bias = (const float*)d_in[8];
  const float* sr   = (const float*)d_in[9];
  const float* lr   = (const float*)d_in[10];

  float* ws = (float*)d_ws;
  short* Xa    = (short*)(ws + 0);         // chain ping-pong (blocked-swz), 4 MB each
  short* Xb    = (short*)(ws + 2097152);
  short* WTpP  = (short*)(ws + 4194304);   // packed bf16 W^T per unit
  short* SiB   = (short*)(ws + 5242880);   // [8192][512] bf16 (b-major, qkv)
  short* XiB   = (short*)(ws + 7340032);   // [1024][512] bf16
  short* WqT   = (short*)(ws + 7602176);   // [m][16][512] bf16
  short* WkT   = (short*)(ws + 7634944);
  short* WvT   = (short*)(ws + 7667712);
  short* WinTP = (short*)(ws + 7700480);   // packed [m]{512 rows, K=128}
  short* WoutT = (short*)(ws + 7962624);   // [512][4096] bf16
  float* Qb    = ws + 9011200;             // [1024][128] fp32
  float* Kb    = ws + 9142272;             // [B,M,N,A] fp32
  float* Vb    = ws + 10190848;
  short* UiBuP = (short*)(ws + 11239424);  // packed [m]{1024 rows, K=128}
  float* norm2 = ws + 13860864;            // 88 used (zeroed 136)
  short* SiBuP = (short*)(ws + 13861376);  // packed [m]{1024 rows, K=512}
  float* pA    = ws + 15958528;            // [1024,8,512] fp32 accA
  float* pB    = ws + 20152832;            // [1024,8,512] fp32 accB
  float* n2tmp = ws + 24347136;            // [8][64] per-tile |W|^2 partials

  float* outYi   = (float*)d_out;            // [1024,512]
  float* outSnew = (float*)d_out + 524288;   // [1024,8,512]

  // ---- merged prep (zero + converts + transposes + W-prep), one launch ----
  k_prep_all<<<3992, 256, 0, stream>>>(Si, Xi, Wq, Wk, Wv, Win, Wout, W,
                                       SiB, SiBuP, XiB, WqT, WkT, WvT, WinTP, WoutT,
                                       Xa, WTpP, outYi, norm2, n2tmp);

  // ---- spectral radius chain + piggybacked qkv (1-4) / attn (5-6) / pre (7-10) ----
  for (int lev = 1; lev <= NLEV; ++lev){
    const short* Xr = (lev & 1) ? Xa : Xb;
    short* Xw       = (lev & 1) ? Xb : Xa;
    const int extraY = (lev <= 4) ? 17 : (lev <= 6 ? 128 : 32);
    k_lev<<<dim3(8, 32 + extraY), 256, 0, stream>>>(Xr, Xw, norm2, n2tmp, lev,
                                                    SiB, XiB, WqT, WkT, WvT, Kb, Vb, Qb, UiBuP,
                                                    SiBuP, WinTP, WTpP, pA, pB);
  }

  // ---- tail: merged finalize (inline rho + Snew) + Yi GEMM, one launch ----
  k_yi2<<<dim3(4, 16, 8), 256, 0, stream>>>(pA, pB, norm2, n2tmp, sr, bias, lr, Si,
                                            WoutT, outSnew, outYi);
}

// Round 12
// 508.218 us; speedup vs baseline: 1.1408x; 1.1408x over previous
//
#include <hip/hip_runtime.h>
#include <hip/hip_bf16.h>

// Problem dims
#define B_ 1024
#define I_ 512
#define O_ 512
#define M_ 8
#define R_ 512
#define A_ 16
#define D_ 128   // M_*A_
#define NLEV 10  // squaring levels; rho via (L10-2L9+L8)/256 (Richardson, validated r11)

using bf16 = __hip_bfloat16;
typedef __attribute__((ext_vector_type(8))) short bf16x8;
typedef __attribute__((ext_vector_type(4))) float f32x4;

__device__ __forceinline__ short f2b(float x){
  __hip_bfloat16 h = __float2bfloat16(x);
  union { __hip_bfloat16 h; short s; } u; u.h = h; return u.s;
}
__device__ __forceinline__ float s2f(short s){
  union { short s[2]; float f; } u; u.s[0] = 0; u.s[1] = s; return u.f;
}
__device__ __forceinline__ float fast_tanh(float x){
  float xx = fminf(fmaxf(x, -9.5f), 9.5f);
  float e2 = __expf(2.f * xx);
  return (e2 - 1.f) / (e2 + 1.f);
}

// Frag-packed layout: matrix [Rows][K] bf16, element (r,k) at
// (r>>4)*(16*K) + (k>>3)*128 + (r&15)*8 + (k&7): fragment load = 1KB burst.
#define PK(r, k, K) (((size_t)((r) >> 4)) * (16 * (K)) + (((k) >> 3) * 128) + (((r) & 15) * 8) + ((k) & 7))

// Blocked-swizzled tile layout for the eigen chain: per unit, 8x8 tiles of
// 64x64 bf16; tile (rt,ct) at (rt*8+ct)*4096 shorts; element (r,c) at
// swz_idx(r,c). gl_lds staging is linear; reads apply the XOR.
__device__ __forceinline__ int swz_idx(int r, int c){
  return r * 64 + (((c >> 3) ^ (r & 7)) << 3) + (c & 7);
}

__device__ __forceinline__ void gl_lds16(const short* g, short* l){
  __builtin_amdgcn_global_load_lds((const __attribute__((address_space(1))) void*)g,
                                   (__attribute__((address_space(3))) void*)l, 16, 0, 0);
}

template<int N> __device__ __forceinline__ void wait_vmcnt(){
  if constexpr (N == 0)      asm volatile("s_waitcnt vmcnt(0)" ::: "memory");
  else if constexpr (N == 4) asm volatile("s_waitcnt vmcnt(4)" ::: "memory");
  else                       asm volatile("s_waitcnt vmcnt(8)" ::: "memory");
}

// ---------------------------------------------------------------------------
// 64x64 inner loop, depth-4 named-register pipeline (r7 proven). Separate A/B
// k-strides (A may be packed, B row-major).
// ---------------------------------------------------------------------------
__device__ __forceinline__ void mm64_d4(const short* __restrict__ A0, const short* __restrict__ B0,
                                        int rOffA, int rOffB, int kStrideA, int kStrideB, int kiters,
                                        f32x4 (&acc)[2][2]){
  const short* A1 = A0 + rOffA;
  const short* B1 = B0 + rOffB;
  bf16x8 a0, a1, b0, b1, c0, c1, d0, d1, e0, e1, f0, f1, g0, g1, h0, h1;
  a0 = *(const bf16x8*)(A0); a1 = *(const bf16x8*)(A1);
  b0 = *(const bf16x8*)(B0); b1 = *(const bf16x8*)(B1);
  if (kiters > 1){
    c0 = *(const bf16x8*)(A0 + kStrideA); c1 = *(const bf16x8*)(A1 + kStrideA);
    d0 = *(const bf16x8*)(B0 + kStrideB); d1 = *(const bf16x8*)(B1 + kStrideB);
  }
  if (kiters > 2){
    e0 = *(const bf16x8*)(A0 + 2 * kStrideA); e1 = *(const bf16x8*)(A1 + 2 * kStrideA);
    f0 = *(const bf16x8*)(B0 + 2 * kStrideB); f1 = *(const bf16x8*)(B1 + 2 * kStrideB);
  }
  if (kiters > 3){
    g0 = *(const bf16x8*)(A0 + 3 * kStrideA); g1 = *(const bf16x8*)(A1 + 3 * kStrideA);
    h0 = *(const bf16x8*)(B0 + 3 * kStrideB); h1 = *(const bf16x8*)(B1 + 3 * kStrideB);
  }
  for (int kk = 0; kk < kiters; ++kk){
    bf16x8 n0, n1, m0, m1;
    if (kk + 4 < kiters){
      n0 = *(const bf16x8*)(A0 + (size_t)(kk + 4) * kStrideA);
      n1 = *(const bf16x8*)(A1 + (size_t)(kk + 4) * kStrideA);
      m0 = *(const bf16x8*)(B0 + (size_t)(kk + 4) * kStrideB);
      m1 = *(const bf16x8*)(B1 + (size_t)(kk + 4) * kStrideB);
    }
    acc[0][0] = __builtin_amdgcn_mfma_f32_16x16x32_bf16(a0, b0, acc[0][0], 0, 0, 0);
    acc[0][1] = __builtin_amdgcn_mfma_f32_16x16x32_bf16(a0, b1, acc[0][1], 0, 0, 0);
    acc[1][0] = __builtin_amdgcn_mfma_f32_16x16x32_bf16(a1, b0, acc[1][0], 0, 0, 0);
    acc[1][1] = __builtin_amdgcn_mfma_f32_16x16x32_bf16(a1, b1, acc[1][1], 0, 0, 0);
    a0 = c0; a1 = c1; b0 = d0; b1 = d1;
    c0 = e0; c1 = e1; d0 = f0; d1 = f1;
    e0 = g0; e1 = g1; f0 = h0; f1 = h1;
    g0 = n0; g1 = n1; h0 = m0; h1 = m1;
  }
}

// ---------------------------------------------------------------------------
// Merged prep kernel: ALL independent converts incl. W-prep.
//   bid 0..511     : zero outYi (bid 0 also zeros norm2 block)
//   bid 512..2815  : cvt (Si->SiB row-major + SiBuP packed ; Xi->XiB)
//   bid 2816..2839 : Wq/Wk/Wv transpose
//   bid 2840..2967 : Win transpose -> WinTP packed
//   bid 2968..3479 : Wout transpose
//   bid 3480..3991 : W -> X0 (blocked-swz) + WTpP packed + norm2tmp[u*64+tile]
// ---------------------------------------------------------------------------
__global__ __launch_bounds__(256) void k_prep_all(
    const float* __restrict__ Si, const float* __restrict__ Xi,
    const float* __restrict__ Wq, const float* __restrict__ Wk, const float* __restrict__ Wv,
    const float* __restrict__ Win, const float* __restrict__ Wout, const float* __restrict__ W,
    short* __restrict__ SiB, short* __restrict__ SiBuP, short* __restrict__ XiB,
    short* __restrict__ WqT, short* __restrict__ WkT, short* __restrict__ WvT,
    short* __restrict__ WinTP, short* __restrict__ WoutT,
    short* __restrict__ X, short* __restrict__ WTpP,
    float* __restrict__ outYi, float* __restrict__ norm2, float* __restrict__ norm2tmp){
  __shared__ short sh[16 * 520];
  const int bid = blockIdx.x, t = threadIdx.x;
  if (bid < 512){
    if (bid == 0){ for (int i = t; i < 136; i += 256) norm2[i] = 0.f; }
    #pragma unroll
    for (int e = 0; e < 4; ++e) outYi[bid * 1024 + e * 256 + t] = 0.f;
  } else if (bid < 2816){
    const int bb0 = bid - 512;
    #pragma unroll
    for (int e = 0; e < 8; ++e){
      int idx = bb0 * 2048 + e * 256 + t;
      if (idx < 4194304){
        short b = f2b(Si[idx]);
        SiB[idx] = b;
        int bb = idx >> 12, mm = (idx >> 9) & 7, cc = idx & 511;
        SiBuP[((size_t)mm << 19) + PK(bb, cc, 512)] = b;
      } else XiB[idx - 4194304] = f2b(Xi[idx - 4194304]);
    }
  } else if (bid < 2840){
    const int i = bid - 2816, which = i / 8, m = i % 8;
    const float* src = (which == 0) ? Wq : (which == 1) ? Wk : Wv;
    short* dst = (which == 0) ? WqT : (which == 1) ? WkT : WvT;
    src += (size_t)m * 8192; dst += (size_t)m * 8192;
    #pragma unroll
    for (int l = 0; l < 32; ++l){
      int idx = l * 256 + t, ii = idx >> 4, a = idx & 15;
      sh[a * 520 + ii] = f2b(src[idx]);
    }
    __syncthreads();
    #pragma unroll
    for (int l = 0; l < 32; ++l){
      int idx = l * 256 + t, a = idx >> 9, ii = idx & 511;
      dst[a * 512 + ii] = sh[a * 520 + ii];
    }
  } else if (bid < 2968){
    // Win [m][128][512] fp32 -> WinTP packed [m]{rows=512(R), K=128(D)}
    const int i = bid - 2840;
    const int x = i & 7, y = (i >> 3) & 1, z = i >> 4;
    const float* src = Win + (size_t)z * 65536;
    const int c0 = x * 64, r0 = y * 64;
    #pragma unroll
    for (int l = 0; l < 16; ++l){
      int idx = l * 256 + t, r = idx >> 6, c = idx & 63;
      sh[r * 66 + c] = f2b(src[(size_t)(r0 + r) * 512 + c0 + c]);
    }
    __syncthreads();
    #pragma unroll
    for (int l = 0; l < 16; ++l){
      int idx = l * 256 + t, r = idx >> 6, c = idx & 63;
      int R2 = c0 + r, K2 = r0 + c;
      WinTP[(size_t)z * 65536 + PK(R2, K2, 128)] = sh[c * 66 + r];
    }
  } else if (bid < 3480){
    const int i = bid - 2968;
    const int x = i & 7, y = i >> 3;
    const int c0 = x * 64, r0 = y * 64;
    #pragma unroll
    for (int l = 0; l < 16; ++l){
      int idx = l * 256 + t, r = idx >> 6, c = idx & 63;
      sh[r * 66 + c] = f2b(Wout[(size_t)(r0 + r) * 512 + c0 + c]);
    }
    __syncthreads();
    #pragma unroll
    for (int l = 0; l < 16; ++l){
      int idx = l * 256 + t, r = idx >> 6, c = idx & 63;
      WoutT[(size_t)(c0 + r) * 4096 + r0 + c] = sh[c * 66 + r];
    }
  } else {
    // W-prep: X0 blocked-swz + WTpP packed + norm2tmp partial
    const int i = bid - 3480, u = i >> 6, tile = i & 63;
    const int rt = tile >> 3, ct = tile & 7;
    const int row0 = rt * 64, col0 = ct * 64;
    const size_t off = (size_t)u * (R_ * R_);
    const size_t tXo = off + (size_t)(rt * 8 + ct) * 4096;
    const int lane = t & 63, wvv = t >> 6;
    float ss = 0.f;
    #pragma unroll
    for (int l = 0; l < 16; ++l){
      int idx = l * 256 + t, r = idx >> 6, c = idx & 63;
      short b = f2b(W[off + (size_t)(row0 + r) * R_ + col0 + c]);
      float vb = s2f(b);
      ss = fmaf(vb, vb, ss);
      X[tXo + swz_idx(r, c)] = b;
      sh[r * 66 + c] = b;
    }
    __syncthreads();
    #pragma unroll
    for (int l = 0; l < 16; ++l){
      int idx = l * 256 + t, r = idx >> 6, c = idx & 63;
      int R2 = col0 + r, K2 = row0 + c;
      WTpP[off + PK(R2, K2, 512)] = sh[c * 66 + r];
    }
    #pragma unroll
    for (int o = 32; o > 0; o >>= 1) ss += __shfl_xor(ss, o, 64);
    __syncthreads();
    float* rf = (float*)sh;
    if (lane == 0) rf[wvv] = ss;
    __syncthreads();
    if (t == 0) norm2tmp[u * 64 + tile] = rf[0] + rf[1] + rf[2] + rf[3];
  }
}

// ---------------------------------------------------------------------------
// Chain level + piggybacked main-pipeline work.
//   yy < 32            : chain — TWO 64x64 tiles per block (yy, yy+32)
//   yy >= 32, lev 1..4 : qkv piggyback (e in [0,136))
//   yy >= 32, lev 5..6 : attn piggyback (e in [0,1024))
//   yy >= 32, lev 7..10: pre-GEMM piggyback (accA/accB -> pA/pB; sscal-free)
// ---------------------------------------------------------------------------
__global__ __launch_bounds__(256, 3) void k_lev(
    const short* __restrict__ Xr, short* __restrict__ Xw,
    float* __restrict__ norm2, const float* __restrict__ norm2tmp, const int lev,
    const short* __restrict__ SiB, const short* __restrict__ XiB,
    const short* __restrict__ WqT, const short* __restrict__ WkT, const short* __restrict__ WvT,
    float* __restrict__ Kb, float* __restrict__ Vb, float* __restrict__ Qb,
    short* __restrict__ UiBuP,
    const short* __restrict__ SiBuP, const short* __restrict__ WinTP, const short* __restrict__ WTpP,
    float* __restrict__ pA, float* __restrict__ pB){
  __shared__ __align__(16) short SA[3][4096];
  __shared__ __align__(16) short SB[3][4096];
  const int u = blockIdx.x, yy = blockIdx.y;
  const int t = threadIdx.x, wv = t >> 6, lane = t & 63;
  const int wr = (wv >> 1) * 32, wc = (wv & 1) * 32;
  const int fm = lane & 15, fq = lane >> 4;

  if (yy >= 32){
    const int e = (yy - 32) * 8 + u;
    if (lev <= 4){
      // ---- qkv piggyback ----
      int z, x, yq;
      if (e < 64)       { z = 0; x = e & 1;         yq = (e >> 1)         + (lev - 1) * 32; }
      else if (e < 128) { z = 1; x = (e - 64) & 1;  yq = ((e - 64) >> 1)  + (lev - 1) * 32; }
      else              { z = 2; x = (e - 128) & 1; yq = ((e - 128) >> 1) + (lev - 1) * 4;  }
      const int ko = fq * 8;
      const int row0 = yq * 64, col0 = x * 64;
      const short* Abase = (z == 2) ? XiB : SiB;
      const short* Bbase = (z == 0) ? WkT : (z == 1) ? WvT : WqT;
      const short* A0 = Abase + (size_t)(row0 + wr + fm) * 512 + ko;
      const short* B0 = Bbase + (size_t)(col0 + wc + fm) * 512 + ko;
      f32x4 zz = {0.f, 0.f, 0.f, 0.f};
      f32x4 acc[2][2] = {{zz, zz}, {zz, zz}};
      mm64_d4(A0, B0, 16 * 512, 16 * 512, 32, 32, 16, acc);
      float* dst = (z == 0) ? Kb : (z == 1) ? Vb : Qb;
      #pragma unroll
      for (int i = 0; i < 2; ++i)
        #pragma unroll
        for (int j = 0; j < 2; ++j)
          #pragma unroll
          for (int r = 0; r < 4; ++r){
            int row = row0 + wr + i * 16 + fq * 4 + r;
            int col = col0 + wc + j * 16 + fm;
            float v = acc[i][j][r];
            if (z == 2) dst[row * 128 + col] = v;
            else {
              int b = row >> 3, n = row & 7, mc = col >> 4, a = col & 15;
              dst[b * 1024 + mc * 128 + n * 16 + a] = v;
            }
          }
    } else if (lev <= 6){
      // ---- attn piggyback (one wave per (b,m)) ----
      float* fsh = (float*)&SA[0][0];
      float* sQ = fsh, *sK = fsh + 512, *sV = fsh + 1024, *sAa = fsh + 1536;
      const int wib = wv;
      const int w = (e + (lev - 5) * 1024) * 4 + wib;
      const int b = w >> 3, m = w & 7;
      for (int e2 = lane; e2 < 128; e2 += 64){
        sQ[wib * 128 + e2] = Qb[b * 128 + e2];
        sK[wib * 128 + e2] = Kb[b * 1024 + m * 128 + e2];
        sV[wib * 128 + e2] = Vb[b * 1024 + m * 128 + e2];
      }
      __syncthreads();
      const int q = lane >> 3, n = lane & 7;
      float s = 0.f;
      #pragma unroll
      for (int a = 0; a < 16; ++a) s = fmaf(sQ[wib * 128 + q * 16 + a], sK[wib * 128 + n * 16 + a], s);
      float mx = s;
      for (int d2 = 1; d2 < 8; d2 <<= 1) mx = fmaxf(mx, __shfl_xor(mx, d2, 64));
      float p = __expf(s - mx);
      float sm = p;
      for (int d2 = 1; d2 < 8; d2 <<= 1) sm += __shfl_xor(sm, d2, 64);
      float ai = p / (sm * 11.313708498984761f);   // softmax then /sqrt(128)
      sAa[wib * 64 + q * 8 + n] = ai;
      __syncthreads();
      for (int e2 = lane; e2 < 128; e2 += 64){
        int q2 = e2 >> 4, a2 = e2 & 15;
        float acc = 0.f;
        #pragma unroll
        for (int n2 = 0; n2 < 8; ++n2) acc = fmaf(sAa[wib * 64 + q2 * 8 + n2], sV[wib * 128 + n2 * 16 + a2], acc);
        UiBuP[(size_t)m * 131072 + PK(b, e2, 128)] = f2b(acc);
      }
    } else {
      // ---- pre-GEMM piggyback: job j of 1024 over levels 7..10 (256/level) ----
      const int j = (lev - 7) * 256 + e;
      if (j >= 1024) return;
      const int m = j & 7, bz = (j >> 3) & 7, by = j >> 6;
      const int row0 = by * 64, col0 = bz * 64;
      const int lo = fm * 8 + fq * 128;
      f32x4 zz = {0.f, 0.f, 0.f, 0.f};
      f32x4 accA[2][2] = {{zz, zz}, {zz, zz}};
      f32x4 accB[2][2] = {{zz, zz}, {zz, zz}};
      {
        const short* A0 = UiBuP + (size_t)m * 131072 + (size_t)(row0 + wr) * 128 + lo;
        const short* B0 = WinTP + (size_t)m * 65536  + (size_t)(col0 + wc) * 128 + lo;
        mm64_d4(A0, B0, 16 * 128, 16 * 128, 512, 512, 4, accA);
      }
      {
        const short* A0 = SiBuP + (size_t)m * 524288 + (size_t)(row0 + wr) * 512 + lo;
        const short* B0 = WTpP  + (size_t)m * 262144 + (size_t)(col0 + wc) * 512 + lo;
        mm64_d4(A0, B0, 16 * 512, 16 * 512, 512, 512, 16, accB);
      }
      #pragma unroll
      for (int i = 0; i < 2; ++i)
        #pragma unroll
        for (int j2 = 0; j2 < 2; ++j2)
          #pragma unroll
          for (int r = 0; r < 4; ++r){
            int b = row0 + wr + i * 16 + fq * 4 + r;
            int c = col0 + wc + j2 * 16 + fm;
            size_t g = ((size_t)b * 8 + m) * 512 + c;
            pA[g] = accA[i][j2][r];
            pB[g] = accB[i][j2][r];
          }
    }
    return;
  }

  // ---- chain: two tiles per block (yy, yy+32) ----
  const size_t off = (size_t)u * (R_ * R_);
  const int swz = (fm & 7) << 4;
  int aof[2][2];
  #pragma unroll
  for (int i = 0; i < 2; ++i)
    #pragma unroll
    for (int kk = 0; kk < 2; ++kk)
      aof[i][kk] = (((wr + fm + i * 16) * 128 + kk * 64 + fq * 16) ^ swz);
  const int c0c = wc + fm,      c0h = c0c >> 3, c0l = c0c & 7;
  const int c1c = wc + 16 + fm, c1h = c1c >> 3, c1l = c1c & 7;
  float n2;
  if (lev == 1){
    n2 = 0.f;
    for (int i = 0; i < 64; ++i) n2 += norm2tmp[u * 64 + i];
  } else {
    n2 = norm2[(lev - 1) * 8 + u];
  }
  const float s2 = 1.f / n2;

  #pragma unroll 1
  for (int half = 0; half < 2; ++half){
    const int tile = yy + half * 32;
    const int rt = tile >> 3, ct = tile & 7;
    const size_t tXo = off + (size_t)(rt * 8 + ct) * 4096;
    const short* gA = Xr + off + (size_t)(rt * 8) * 4096 + t * 8;  // A tiles (rt,kt): +4096/kt
    const short* gB = Xr + off + (size_t)ct * 4096 + t * 8;        // B tiles (kt,ct): +32768/kt

    __syncthreads();   // protect LDS reuse across halves
    // prologue: stage tiles 0,1
    #pragma unroll
    for (int p = 0; p < 2; ++p){
      short* dA = &SA[p][0] + wv * 512;
      short* dB = &SB[p][0] + wv * 512;
      gl_lds16(gA + (size_t)p * 4096,         dA);
      gl_lds16(gA + (size_t)p * 4096 + 2048,  dA + 2048);
      gl_lds16(gB + (size_t)p * 32768,        dB);
      gl_lds16(gB + (size_t)p * 32768 + 2048, dB + 2048);
    }
    f32x4 zz = {0.f, 0.f, 0.f, 0.f};
    f32x4 acc[2][2] = {{zz, zz}, {zz, zz}};
    #pragma unroll
    for (int kt = 0; kt < 8; ++kt){
      if (kt < 7) wait_vmcnt<4>();
      else        wait_vmcnt<0>();
      __builtin_amdgcn_s_barrier();
      if (kt < 6){
        const int b = (kt + 2) % 3;
        short* dA = &SA[b][0] + wv * 512;
        short* dB = &SB[b][0] + wv * 512;
        gl_lds16(gA + (size_t)(kt + 2) * 4096,         dA);
        gl_lds16(gA + (size_t)(kt + 2) * 4096 + 2048,  dA + 2048);
        gl_lds16(gB + (size_t)(kt + 2) * 32768,        dB);
        gl_lds16(gB + (size_t)(kt + 2) * 32768 + 2048, dB + 2048);
      }
      const char*  Ab = (const char*)&SA[kt % 3][0];
      const short* Bb = &SB[kt % 3][0];
      #pragma unroll
      for (int kk = 0; kk < 2; ++kk){
        bf16x8 a0 = *(const bf16x8*)(Ab + aof[0][kk]);
        bf16x8 a1 = *(const bf16x8*)(Ab + aof[1][kk]);
        bf16x8 b0, b1;
        #pragma unroll
        for (int e = 0; e < 8; ++e){
          int rb = (kk * 32 + fq * 8 + e) * 64;
          b0[e] = Bb[rb + ((c0h ^ e) << 3) + c0l];
          b1[e] = Bb[rb + ((c1h ^ e) << 3) + c1l];
        }
        acc[0][0] = __builtin_amdgcn_mfma_f32_16x16x32_bf16(a0, b0, acc[0][0], 0, 0, 0);
        acc[0][1] = __builtin_amdgcn_mfma_f32_16x16x32_bf16(a0, b1, acc[0][1], 0, 0, 0);
        acc[1][0] = __builtin_amdgcn_mfma_f32_16x16x32_bf16(a1, b0, acc[1][0], 0, 0, 0);
        acc[1][1] = __builtin_amdgcn_mfma_f32_16x16x32_bf16(a1, b1, acc[1][1], 0, 0, 0);
      }
    }
    // epilogue: swizzled X' image in SA[0], linear full-line stores
    float ss = 0.f;
    #pragma unroll
    for (int i = 0; i < 2; ++i)
      #pragma unroll
      for (int j = 0; j < 2; ++j)
        #pragma unroll
        for (int r = 0; r < 4; ++r){
          int lr = wr + i * 16 + fq * 4 + r, lc = wc + j * 16 + fm;
          short b = f2b(acc[i][j][r] * s2);
          float vb = s2f(b);
          ss = fmaf(vb, vb, ss);
          SA[0][swz_idx(lr, lc)] = b;
        }
    __syncthreads();
    *(bf16x8*)(Xw + tXo + t * 8)        = *(const bf16x8*)(&SA[0][t * 8]);
    *(bf16x8*)(Xw + tXo + 2048 + t * 8) = *(const bf16x8*)(&SA[0][2048 + t * 8]);
    #pragma unroll
    for (int o = 32; o > 0; o >>= 1) ss += __shfl_xor(ss, o, 64);
    if (lane == 0) atomicAdd(&norm2[lev * 8 + u], ss);
  }
}

// ---------------------------------------------------------------------------
// Final elementwise (r10 proven): each block computes sscal[m] inline from
// norm2/norm2tmp (Richardson at NLEV), then Snew = (1-lr)Si + lr tanh(...)
// from precomputed pA/pB. Pure streaming, coalesced.
// ---------------------------------------------------------------------------
__global__ __launch_bounds__(256) void k_fin(const float* __restrict__ pA, const float* __restrict__ pB,
                                             const float* __restrict__ norm2, const float* __restrict__ norm2tmp,
                                             const float* __restrict__ sr, const float* __restrict__ bias,
                                             const float* __restrict__ lr, const float* __restrict__ Si,
                                             float* __restrict__ outSnew, short* __restrict__ SnewB){
  const int m = blockIdx.x, by = blockIdx.y, bz = blockIdx.z;
  const int t = threadIdx.x;
  // inline rho for unit m (Richardson second difference at j=NLEV)
  float n0 = 0.f;
  for (int i = 0; i < 64; ++i) n0 += norm2tmp[m * 64 + i];
  float L = 0.5f * logf(n0), L8 = 0.f, L9 = 0.f, L10 = 0.f;
  for (int j = 1; j <= NLEV; ++j){
    L = 2.f * L + 0.5f * logf(norm2[j * 8 + m]);
    if (j == NLEV - 2) L8  = L;
    if (j == NLEV - 1) L9  = L;
    if (j == NLEV)     L10 = L;
  }
  const float sc = sr[m] / expf((L10 - 2.f * L9 + L8) * (1.f / 256.f));
  const float lm = lr[m];
  const int row0 = by * 64, col0 = bz * 64;
  #pragma unroll
  for (int l = 0; l < 16; ++l){
    int idx = l * 256 + t, r = idx >> 6, c = idx & 63;
    size_t g = ((size_t)(row0 + r) * 8 + m) * 512 + col0 + c;
    float pre = pA[g] + sc * pB[g] + bias[m * 512 + col0 + c];
    float sn = (1.f - lm) * Si[g] + lm * fast_tanh(pre);
    outSnew[g] = sn;
    SnewB[g] = f2b(sn);
  }
}

// ---------------------------------------------------------------------------
// Yi GEMM (r10 proven): A = SnewB [1024][4096], B = WoutT [512][4096];
// split-K=4 atomics, depth-4 pipeline.
// ---------------------------------------------------------------------------
__global__ __launch_bounds__(256) void k_yi(const short* __restrict__ SnewB, const short* __restrict__ WoutT,
                                            float* __restrict__ outYi){
  const int t = threadIdx.x, wv = t >> 6, lane = t & 63;
  const int wr = (wv >> 1) * 32, wc = (wv & 1) * 32;
  const int fm = lane & 15, fq = lane >> 4, ko = fq * 8;
  const int row0 = blockIdx.y * 64, col0 = blockIdx.x * 64;
  const int kbeg = blockIdx.z * 1024;
  const short* A0 = SnewB + (size_t)(row0 + wr + fm) * 4096 + kbeg + ko;
  const short* B0 = WoutT + (size_t)(col0 + wc + fm) * 4096 + kbeg + ko;
  f32x4 zz = {0.f, 0.f, 0.f, 0.f};
  f32x4 acc[2][2] = {{zz, zz}, {zz, zz}};
  mm64_d4(A0, B0, 16 * 4096, 16 * 4096, 32, 32, 32, acc);
  #pragma unroll
  for (int i = 0; i < 2; ++i)
    #pragma unroll
    for (int j = 0; j < 2; ++j)
      #pragma unroll
      for (int r = 0; r < 4; ++r){
        int row = row0 + wr + i * 16 + fq * 4 + r;
        int col = col0 + wc + j * 16 + fm;
        atomicAdd(&outYi[row * 512 + col], acc[i][j][r]);
      }
}

// ---------------------------------------------------------------------------
extern "C" void kernel_launch(void* const* d_in, const int* in_sizes, int n_in,
                              void* d_out, int out_size, void* d_ws, size_t ws_size,
                              hipStream_t stream) {
  const float* Xi   = (const float*)d_in[0];
  const float* Si   = (const float*)d_in[1];
  const float* Wq   = (const float*)d_in[2];
  const float* Wk   = (const float*)d_in[3];
  const float* Wv   = (const float*)d_in[4];
  const float* Wout = (const float*)d_in[5];
  const float* W    = (const float*)d_in[6];
  const float* Win  = (const float*)d_in[7];
  const float* bias = (const float*)d_in[8];
  const float* sr   = (const float*)d_in[9];
  const float* lr   = (const float*)d_in[10];

  float* ws = (float*)d_ws;
  short* Xa    = (short*)(ws + 0);         // chain ping-pong (blocked-swz), 4 MB each
  short* Xb    = (short*)(ws + 2097152);
  short* WTpP  = (short*)(ws + 4194304);   // packed bf16 W^T per unit
  short* SiB   = (short*)(ws + 5242880);   // [8192][512] bf16 (b-major, qkv)
  short* XiB   = (short*)(ws + 7340032);   // [1024][512] bf16
  short* WqT   = (short*)(ws + 7602176);   // [m][16][512] bf16
  short* WkT   = (short*)(ws + 7634944);
  short* WvT   = (short*)(ws + 7667712);
  short* WinTP = (short*)(ws + 7700480);   // packed [m]{512 rows, K=128}
  short* WoutT = (short*)(ws + 7962624);   // [512][4096] bf16
  float* Qb    = ws + 9011200;             // [1024][128] fp32
  float* Kb    = ws + 9142272;             // [B,M,N,A] fp32
  float* Vb    = ws + 10190848;
  short* UiBuP = (short*)(ws + 11239424);  // packed [m]{1024 rows, K=128}
  short* SnewB = (short*)(ws + 11763712);  // [1024][4096] bf16
  float* norm2 = ws + 13860864;            // 88 used (zeroed 136)
  short* SiBuP = (short*)(ws + 13861376);  // packed [m]{1024 rows, K=512}
  float* pA    = ws + 15958528;            // [1024,8,512] fp32 accA
  float* pB    = ws + 20152832;            // [1024,8,512] fp32 accB
  float* n2tmp = ws + 24347136;            // [8][64] per-tile |W|^2 partials

  float* outYi   = (float*)d_out;            // [1024,512]
  float* outSnew = (float*)d_out + 524288;   // [1024,8,512]

  // ---- merged prep (zero + converts + transposes + W-prep), one launch ----
  k_prep_all<<<3992, 256, 0, stream>>>(Si, Xi, Wq, Wk, Wv, Win, Wout, W,
                                       SiB, SiBuP, XiB, WqT, WkT, WvT, WinTP, WoutT,
                                       Xa, WTpP, outYi, norm2, n2tmp);

  // ---- spectral radius chain + piggybacked qkv (1-4) / attn (5-6) / pre (7-10) ----
  for (int lev = 1; lev <= NLEV; ++lev){
    const short* Xr = (lev & 1) ? Xa : Xb;
    short* Xw       = (lev & 1) ? Xb : Xa;
    const int extraY = (lev <= 4) ? 17 : (lev <= 6 ? 128 : 32);
    k_lev<<<dim3(8, 32 + extraY), 256, 0, stream>>>(Xr, Xw, norm2, n2tmp, lev,
                                                    SiB, XiB, WqT, WkT, WvT, Kb, Vb, Qb, UiBuP,
                                                    SiBuP, WinTP, WTpP, pA, pB);
  }

  // ---- tail: finalize (inline rho + Snew) then Yi GEMM (r10 proven) ----
  k_fin<<<dim3(8, 16, 8), 256, 0, stream>>>(pA, pB, norm2, n2tmp, sr, bias, lr, Si, outSnew, SnewB);
  k_yi<<<dim3(8, 16, 4), 256, 0, stream>>>(SnewB, WoutT, outYi);
}

// Round 13
// 484.079 us; speedup vs baseline: 1.1977x; 1.0499x over previous
//
#include <hip/hip_runtime.h>
#include <hip/hip_bf16.h>

// Problem dims
#define B_ 1024
#define I_ 512
#define O_ 512
#define M_ 8
#define R_ 512
#define A_ 16
#define D_ 128   // M_*A_
#define NLEV 9   // squaring levels; rho via (L9-2L8+L7)/128 (Richardson)

using bf16 = __hip_bfloat16;
typedef __attribute__((ext_vector_type(8))) short bf16x8;
typedef __attribute__((ext_vector_type(4))) float f32x4;

__device__ __forceinline__ short f2b(float x){
  __hip_bfloat16 h = __float2bfloat16(x);
  union { __hip_bfloat16 h; short s; } u; u.h = h; return u.s;
}
__device__ __forceinline__ float s2f(short s){
  union { short s[2]; float f; } u; u.s[0] = 0; u.s[1] = s; return u.f;
}
__device__ __forceinline__ float fast_tanh(float x){
  float xx = fminf(fmaxf(x, -9.5f), 9.5f);
  float e2 = __expf(2.f * xx);
  return (e2 - 1.f) / (e2 + 1.f);
}

// Frag-packed layout: matrix [Rows][K] bf16, element (r,k) at
// (r>>4)*(16*K) + (k>>3)*128 + (r&15)*8 + (k&7): fragment load = 1KB burst.
#define PK(r, k, K) (((size_t)((r) >> 4)) * (16 * (K)) + (((k) >> 3) * 128) + (((r) & 15) * 8) + ((k) & 7))

// Blocked-swizzled tile layout for the eigen chain: per unit, 8x8 tiles of
// 64x64 bf16; tile (rt,ct) at (rt*8+ct)*4096 shorts; element (r,c) at
// swz_idx(r,c). gl_lds staging is linear; reads apply the XOR.
__device__ __forceinline__ int swz_idx(int r, int c){
  return r * 64 + (((c >> 3) ^ (r & 7)) << 3) + (c & 7);
}

__device__ __forceinline__ void gl_lds16(const short* g, short* l){
  __builtin_amdgcn_global_load_lds((const __attribute__((address_space(1))) void*)g,
                                   (__attribute__((address_space(3))) void*)l, 16, 0, 0);
}

template<int N> __device__ __forceinline__ void wait_vmcnt(){
  if constexpr (N == 0)      asm volatile("s_waitcnt vmcnt(0)" ::: "memory");
  else if constexpr (N == 4) asm volatile("s_waitcnt vmcnt(4)" ::: "memory");
  else                       asm volatile("s_waitcnt vmcnt(8)" ::: "memory");
}

// ---------------------------------------------------------------------------
// 64x64 inner loop, depth-4 named-register pipeline (r7 proven). Separate A/B
// k-strides (A may be packed/LDS, B row-major).
// ---------------------------------------------------------------------------
__device__ __forceinline__ void mm64_d4(const short* __restrict__ A0, const short* __restrict__ B0,
                                        int rOffA, int rOffB, int kStrideA, int kStrideB, int kiters,
                                        f32x4 (&acc)[2][2]){
  const short* A1 = A0 + rOffA;
  const short* B1 = B0 + rOffB;
  bf16x8 a0, a1, b0, b1, c0, c1, d0, d1, e0, e1, f0, f1, g0, g1, h0, h1;
  a0 = *(const bf16x8*)(A0); a1 = *(const bf16x8*)(A1);
  b0 = *(const bf16x8*)(B0); b1 = *(const bf16x8*)(B1);
  if (kiters > 1){
    c0 = *(const bf16x8*)(A0 + kStrideA); c1 = *(const bf16x8*)(A1 + kStrideA);
    d0 = *(const bf16x8*)(B0 + kStrideB); d1 = *(const bf16x8*)(B1 + kStrideB);
  }
  if (kiters > 2){
    e0 = *(const bf16x8*)(A0 + 2 * kStrideA); e1 = *(const bf16x8*)(A1 + 2 * kStrideA);
    f0 = *(const bf16x8*)(B0 + 2 * kStrideB); f1 = *(const bf16x8*)(B1 + 2 * kStrideB);
  }
  if (kiters > 3){
    g0 = *(const bf16x8*)(A0 + 3 * kStrideA); g1 = *(const bf16x8*)(A1 + 3 * kStrideA);
    h0 = *(const bf16x8*)(B0 + 3 * kStrideB); h1 = *(const bf16x8*)(B1 + 3 * kStrideB);
  }
  for (int kk = 0; kk < kiters; ++kk){
    bf16x8 n0, n1, m0, m1;
    if (kk + 4 < kiters){
      n0 = *(const bf16x8*)(A0 + (size_t)(kk + 4) * kStrideA);
      n1 = *(const bf16x8*)(A1 + (size_t)(kk + 4) * kStrideA);
      m0 = *(const bf16x8*)(B0 + (size_t)(kk + 4) * kStrideB);
      m1 = *(const bf16x8*)(B1 + (size_t)(kk + 4) * kStrideB);
    }
    acc[0][0] = __builtin_amdgcn_mfma_f32_16x16x32_bf16(a0, b0, acc[0][0], 0, 0, 0);
    acc[0][1] = __builtin_amdgcn_mfma_f32_16x16x32_bf16(a0, b1, acc[0][1], 0, 0, 0);
    acc[1][0] = __builtin_amdgcn_mfma_f32_16x16x32_bf16(a1, b0, acc[1][0], 0, 0, 0);
    acc[1][1] = __builtin_amdgcn_mfma_f32_16x16x32_bf16(a1, b1, acc[1][1], 0, 0, 0);
    a0 = c0; a1 = c1; b0 = d0; b1 = d1;
    c0 = e0; c1 = e1; d0 = f0; d1 = f1;
    e0 = g0; e1 = g1; f0 = h0; f1 = h1;
    g0 = n0; g1 = n1; h0 = m0; h1 = m1;
  }
}

// ---------------------------------------------------------------------------
// Merged prep kernel: ALL independent converts incl. W-prep.
//   bid 0..511     : zero outYi (bid 0 also zeros norm2 block)
//   bid 512..2815  : cvt (Si->SiB row-major + SiBuP packed ; Xi->XiB)
//   bid 2816..2839 : Wq/Wk/Wv transpose
//   bid 2840..2967 : Win transpose -> WinTP packed
//   bid 2968..3479 : Wout transpose
//   bid 3480..3991 : W -> X0 (blocked-swz) + WTpP packed + norm2tmp[u*64+tile]
// ---------------------------------------------------------------------------
__global__ __launch_bounds__(256) void k_prep_all(
    const float* __restrict__ Si, const float* __restrict__ Xi,
    const float* __restrict__ Wq, const float* __restrict__ Wk, const float* __restrict__ Wv,
    const float* __restrict__ Win, const float* __restrict__ Wout, const float* __restrict__ W,
    short* __restrict__ SiB, short* __restrict__ SiBuP, short* __restrict__ XiB,
    short* __restrict__ WqT, short* __restrict__ WkT, short* __restrict__ WvT,
    short* __restrict__ WinTP, short* __restrict__ WoutT,
    short* __restrict__ X, short* __restrict__ WTpP,
    float* __restrict__ outYi, float* __restrict__ norm2, float* __restrict__ norm2tmp){
  __shared__ short sh[16 * 520];
  const int bid = blockIdx.x, t = threadIdx.x;
  if (bid < 512){
    if (bid == 0){ for (int i = t; i < 136; i += 256) norm2[i] = 0.f; }
    #pragma unroll
    for (int e = 0; e < 4; ++e) outYi[bid * 1024 + e * 256 + t] = 0.f;
  } else if (bid < 2816){
    const int bb0 = bid - 512;
    #pragma unroll
    for (int e = 0; e < 8; ++e){
      int idx = bb0 * 2048 + e * 256 + t;
      if (idx < 4194304){
        short b = f2b(Si[idx]);
        SiB[idx] = b;
        int bb = idx >> 12, mm = (idx >> 9) & 7, cc = idx & 511;
        SiBuP[((size_t)mm << 19) + PK(bb, cc, 512)] = b;
      } else XiB[idx - 4194304] = f2b(Xi[idx - 4194304]);
    }
  } else if (bid < 2840){
    const int i = bid - 2816, which = i / 8, m = i % 8;
    const float* src = (which == 0) ? Wq : (which == 1) ? Wk : Wv;
    short* dst = (which == 0) ? WqT : (which == 1) ? WkT : WvT;
    src += (size_t)m * 8192; dst += (size_t)m * 8192;
    #pragma unroll
    for (int l = 0; l < 32; ++l){
      int idx = l * 256 + t, ii = idx >> 4, a = idx & 15;
      sh[a * 520 + ii] = f2b(src[idx]);
    }
    __syncthreads();
    #pragma unroll
    for (int l = 0; l < 32; ++l){
      int idx = l * 256 + t, a = idx >> 9, ii = idx & 511;
      dst[a * 512 + ii] = sh[a * 520 + ii];
    }
  } else if (bid < 2968){
    // Win [m][128][512] fp32 -> WinTP packed [m]{rows=512(R), K=128(D)}
    const int i = bid - 2840;
    const int x = i & 7, y = (i >> 3) & 1, z = i >> 4;
    const float* src = Win + (size_t)z * 65536;
    const int c0 = x * 64, r0 = y * 64;
    #pragma unroll
    for (int l = 0; l < 16; ++l){
      int idx = l * 256 + t, r = idx >> 6, c = idx & 63;
      sh[r * 66 + c] = f2b(src[(size_t)(r0 + r) * 512 + c0 + c]);
    }
    __syncthreads();
    #pragma unroll
    for (int l = 0; l < 16; ++l){
      int idx = l * 256 + t, r = idx >> 6, c = idx & 63;
      int R2 = c0 + r, K2 = r0 + c;
      WinTP[(size_t)z * 65536 + PK(R2, K2, 128)] = sh[c * 66 + r];
    }
  } else if (bid < 3480){
    const int i = bid - 2968;
    const int x = i & 7, y = i >> 3;
    const int c0 = x * 64, r0 = y * 64;
    #pragma unroll
    for (int l = 0; l < 16; ++l){
      int idx = l * 256 + t, r = idx >> 6, c = idx & 63;
      sh[r * 66 + c] = f2b(Wout[(size_t)(r0 + r) * 512 + c0 + c]);
    }
    __syncthreads();
    #pragma unroll
    for (int l = 0; l < 16; ++l){
      int idx = l * 256 + t, r = idx >> 6, c = idx & 63;
      WoutT[(size_t)(c0 + r) * 4096 + r0 + c] = sh[c * 66 + r];
    }
  } else {
    // W-prep: X0 blocked-swz + WTpP packed + norm2tmp partial
    const int i = bid - 3480, u = i >> 6, tile = i & 63;
    const int rt = tile >> 3, ct = tile & 7;
    const int row0 = rt * 64, col0 = ct * 64;
    const size_t off = (size_t)u * (R_ * R_);
    const size_t tXo = off + (size_t)(rt * 8 + ct) * 4096;
    const int lane = t & 63, wvv = t >> 6;
    float ss = 0.f;
    #pragma unroll
    for (int l = 0; l < 16; ++l){
      int idx = l * 256 + t, r = idx >> 6, c = idx & 63;
      short b = f2b(W[off + (size_t)(row0 + r) * R_ + col0 + c]);
      float vb = s2f(b);
      ss = fmaf(vb, vb, ss);
      X[tXo + swz_idx(r, c)] = b;
      sh[r * 66 + c] = b;
    }
    __syncthreads();
    #pragma unroll
    for (int l = 0; l < 16; ++l){
      int idx = l * 256 + t, r = idx >> 6, c = idx & 63;
      int R2 = col0 + r, K2 = row0 + c;
      WTpP[off + PK(R2, K2, 512)] = sh[c * 66 + r];
    }
    #pragma unroll
    for (int o = 32; o > 0; o >>= 1) ss += __shfl_xor(ss, o, 64);
    __syncthreads();
    float* rf = (float*)sh;
    if (lane == 0) rf[wvv] = ss;
    __syncthreads();
    if (t == 0) norm2tmp[u * 64 + tile] = rf[0] + rf[1] + rf[2] + rf[3];
  }
}

// ---------------------------------------------------------------------------
// Chain level + piggybacked main-pipeline work.
//   yy < 32            : chain — TWO 64x64 tiles per block (yy, yy+32)
//   yy >= 32, lev 1..4 : qkv piggyback (e in [0,136))
//   yy >= 32, lev 5..6 : attn piggyback (e in [0,1024))
//   yy >= 32, lev 7..9 : pre-GEMM piggyback (344 jobs/level, disjoint)
// ---------------------------------------------------------------------------
__global__ __launch_bounds__(256, 3) void k_lev(
    const short* __restrict__ Xr, short* __restrict__ Xw,
    float* __restrict__ norm2, const float* __restrict__ norm2tmp, const int lev,
    const short* __restrict__ SiB, const short* __restrict__ XiB,
    const short* __restrict__ WqT, const short* __restrict__ WkT, const short* __restrict__ WvT,
    float* __restrict__ Kb, float* __restrict__ Vb, float* __restrict__ Qb,
    short* __restrict__ UiBuP,
    const short* __restrict__ SiBuP, const short* __restrict__ WinTP, const short* __restrict__ WTpP,
    float* __restrict__ pA, float* __restrict__ pB){
  __shared__ __align__(16) short SA[3][4096];
  __shared__ __align__(16) short SB[3][4096];
  const int u = blockIdx.x, yy = blockIdx.y;
  const int t = threadIdx.x, wv = t >> 6, lane = t & 63;
  const int wr = (wv >> 1) * 32, wc = (wv & 1) * 32;
  const int fm = lane & 15, fq = lane >> 4;

  if (yy >= 32){
    const int e = (yy - 32) * 8 + u;
    if (lev <= 4){
      // ---- qkv piggyback ----
      int z, x, yq;
      if (e < 64)       { z = 0; x = e & 1;         yq = (e >> 1)         + (lev - 1) * 32; }
      else if (e < 128) { z = 1; x = (e - 64) & 1;  yq = ((e - 64) >> 1)  + (lev - 1) * 32; }
      else              { z = 2; x = (e - 128) & 1; yq = ((e - 128) >> 1) + (lev - 1) * 4;  }
      const int ko = fq * 8;
      const int row0 = yq * 64, col0 = x * 64;
      const short* Abase = (z == 2) ? XiB : SiB;
      const short* Bbase = (z == 0) ? WkT : (z == 1) ? WvT : WqT;
      const short* A0 = Abase + (size_t)(row0 + wr + fm) * 512 + ko;
      const short* B0 = Bbase + (size_t)(col0 + wc + fm) * 512 + ko;
      f32x4 zz = {0.f, 0.f, 0.f, 0.f};
      f32x4 acc[2][2] = {{zz, zz}, {zz, zz}};
      mm64_d4(A0, B0, 16 * 512, 16 * 512, 32, 32, 16, acc);
      float* dst = (z == 0) ? Kb : (z == 1) ? Vb : Qb;
      #pragma unroll
      for (int i = 0; i < 2; ++i)
        #pragma unroll
        for (int j = 0; j < 2; ++j)
          #pragma unroll
          for (int r = 0; r < 4; ++r){
            int row = row0 + wr + i * 16 + fq * 4 + r;
            int col = col0 + wc + j * 16 + fm;
            float v = acc[i][j][r];
            if (z == 2) dst[row * 128 + col] = v;
            else {
              int b = row >> 3, n = row & 7, mc = col >> 4, a = col & 15;
              dst[b * 1024 + mc * 128 + n * 16 + a] = v;
            }
          }
    } else if (lev <= 6){
      // ---- attn piggyback (one wave per (b,m)) ----
      float* fsh = (float*)&SA[0][0];
      float* sQ = fsh, *sK = fsh + 512, *sV = fsh + 1024, *sAa = fsh + 1536;
      const int wib = wv;
      const int w = (e + (lev - 5) * 1024) * 4 + wib;
      const int b = w >> 3, m = w & 7;
      for (int e2 = lane; e2 < 128; e2 += 64){
        sQ[wib * 128 + e2] = Qb[b * 128 + e2];
        sK[wib * 128 + e2] = Kb[b * 1024 + m * 128 + e2];
        sV[wib * 128 + e2] = Vb[b * 1024 + m * 128 + e2];
      }
      __syncthreads();
      const int q = lane >> 3, n = lane & 7;
      float s = 0.f;
      #pragma unroll
      for (int a = 0; a < 16; ++a) s = fmaf(sQ[wib * 128 + q * 16 + a], sK[wib * 128 + n * 16 + a], s);
      float mx = s;
      for (int d2 = 1; d2 < 8; d2 <<= 1) mx = fmaxf(mx, __shfl_xor(mx, d2, 64));
      float p = __expf(s - mx);
      float sm = p;
      for (int d2 = 1; d2 < 8; d2 <<= 1) sm += __shfl_xor(sm, d2, 64);
      float ai = p / (sm * 11.313708498984761f);   // softmax then /sqrt(128)
      sAa[wib * 64 + q * 8 + n] = ai;
      __syncthreads();
      for (int e2 = lane; e2 < 128; e2 += 64){
        int q2 = e2 >> 4, a2 = e2 & 15;
        float acc = 0.f;
        #pragma unroll
        for (int n2 = 0; n2 < 8; ++n2) acc = fmaf(sAa[wib * 64 + q2 * 8 + n2], sV[wib * 128 + n2 * 16 + a2], acc);
        UiBuP[(size_t)m * 131072 + PK(b, e2, 128)] = f2b(acc);
      }
    } else {
      // ---- pre-GEMM piggyback: job j of 1024 over levels 7..9 (344/level) ----
      const int j = (lev - 7) * 344 + e;
      if (j >= 1024) return;
      const int m = j & 7, bz = (j >> 3) & 7, by = j >> 6;
      const int row0 = by * 64, col0 = bz * 64;
      const int lo = fm * 8 + fq * 128;
      f32x4 zz = {0.f, 0.f, 0.f, 0.f};
      f32x4 accA[2][2] = {{zz, zz}, {zz, zz}};
      f32x4 accB[2][2] = {{zz, zz}, {zz, zz}};
      {
        const short* A0 = UiBuP + (size_t)m * 131072 + (size_t)(row0 + wr) * 128 + lo;
        const short* B0 = WinTP + (size_t)m * 65536  + (size_t)(col0 + wc) * 128 + lo;
        mm64_d4(A0, B0, 16 * 128, 16 * 128, 512, 512, 4, accA);
      }
      {
        const short* A0 = SiBuP + (size_t)m * 524288 + (size_t)(row0 + wr) * 512 + lo;
        const short* B0 = WTpP  + (size_t)m * 262144 + (size_t)(col0 + wc) * 512 + lo;
        mm64_d4(A0, B0, 16 * 512, 16 * 512, 512, 512, 16, accB);
      }
      #pragma unroll
      for (int i = 0; i < 2; ++i)
        #pragma unroll
        for (int j2 = 0; j2 < 2; ++j2)
          #pragma unroll
          for (int r = 0; r < 4; ++r){
            int b = row0 + wr + i * 16 + fq * 4 + r;
            int c = col0 + wc + j2 * 16 + fm;
            size_t g = ((size_t)b * 8 + m) * 512 + c;
            pA[g] = accA[i][j2][r];
            pB[g] = accB[i][j2][r];
          }
    }
    return;
  }

  // ---- chain: two tiles per block (yy, yy+32) ----
  const size_t off = (size_t)u * (R_ * R_);
  const int swz = (fm & 7) << 4;
  int aof[2][2];
  #pragma unroll
  for (int i = 0; i < 2; ++i)
    #pragma unroll
    for (int kk = 0; kk < 2; ++kk)
      aof[i][kk] = (((wr + fm + i * 16) * 128 + kk * 64 + fq * 16) ^ swz);
  const int c0c = wc + fm,      c0h = c0c >> 3, c0l = c0c & 7;
  const int c1c = wc + 16 + fm, c1h = c1c >> 3, c1l = c1c & 7;
  float n2;
  if (lev == 1){
    n2 = 0.f;
    for (int i = 0; i < 64; ++i) n2 += norm2tmp[u * 64 + i];
  } else {
    n2 = norm2[(lev - 1) * 8 + u];
  }
  const float s2 = 1.f / n2;

  #pragma unroll 1
  for (int half = 0; half < 2; ++half){
    const int tile = yy + half * 32;
    const int rt = tile >> 3, ct = tile & 7;
    const size_t tXo = off + (size_t)(rt * 8 + ct) * 4096;
    const short* gA = Xr + off + (size_t)(rt * 8) * 4096 + t * 8;  // A tiles (rt,kt): +4096/kt
    const short* gB = Xr + off + (size_t)ct * 4096 + t * 8;        // B tiles (kt,ct): +32768/kt

    __syncthreads();   // protect LDS reuse across halves
    // prologue: stage tiles 0,1
    #pragma unroll
    for (int p = 0; p < 2; ++p){
      short* dA = &SA[p][0] + wv * 512;
      short* dB = &SB[p][0] + wv * 512;
      gl_lds16(gA + (size_t)p * 4096,         dA);
      gl_lds16(gA + (size_t)p * 4096 + 2048,  dA + 2048);
      gl_lds16(gB + (size_t)p * 32768,        dB);
      gl_lds16(gB + (size_t)p * 32768 + 2048, dB + 2048);
    }
    f32x4 zz = {0.f, 0.f, 0.f, 0.f};
    f32x4 acc[2][2] = {{zz, zz}, {zz, zz}};
    #pragma unroll
    for (int kt = 0; kt < 8; ++kt){
      if (kt < 7) wait_vmcnt<4>();
      else        wait_vmcnt<0>();
      __builtin_amdgcn_s_barrier();
      if (kt < 6){
        const int b = (kt + 2) % 3;
        short* dA = &SA[b][0] + wv * 512;
        short* dB = &SB[b][0] + wv * 512;
        gl_lds16(gA + (size_t)(kt + 2) * 4096,         dA);
        gl_lds16(gA + (size_t)(kt + 2) * 4096 + 2048,  dA + 2048);
        gl_lds16(gB + (size_t)(kt + 2) * 32768,        dB);
        gl_lds16(gB + (size_t)(kt + 2) * 32768 + 2048, dB + 2048);
      }
      const char*  Ab = (const char*)&SA[kt % 3][0];
      const short* Bb = &SB[kt % 3][0];
      #pragma unroll
      for (int kk = 0; kk < 2; ++kk){
        bf16x8 a0 = *(const bf16x8*)(Ab + aof[0][kk]);
        bf16x8 a1 = *(const bf16x8*)(Ab + aof[1][kk]);
        bf16x8 b0, b1;
        #pragma unroll
        for (int e = 0; e < 8; ++e){
          int rb = (kk * 32 + fq * 8 + e) * 64;
          b0[e] = Bb[rb + ((c0h ^ e) << 3) + c0l];
          b1[e] = Bb[rb + ((c1h ^ e) << 3) + c1l];
        }
        acc[0][0] = __builtin_amdgcn_mfma_f32_16x16x32_bf16(a0, b0, acc[0][0], 0, 0, 0);
        acc[0][1] = __builtin_amdgcn_mfma_f32_16x16x32_bf16(a0, b1, acc[0][1], 0, 0, 0);
        acc[1][0] = __builtin_amdgcn_mfma_f32_16x16x32_bf16(a1, b0, acc[1][0], 0, 0, 0);
        acc[1][1] = __builtin_amdgcn_mfma_f32_16x16x32_bf16(a1, b1, acc[1][1], 0, 0, 0);
      }
    }
    // epilogue: swizzled X' image in SA[0], linear full-line stores
    float ss = 0.f;
    #pragma unroll
    for (int i = 0; i < 2; ++i)
      #pragma unroll
      for (int j = 0; j < 2; ++j)
        #pragma unroll
        for (int r = 0; r < 4; ++r){
          int lr = wr + i * 16 + fq * 4 + r, lc = wc + j * 16 + fm;
          short b = f2b(acc[i][j][r] * s2);
          float vb = s2f(b);
          ss = fmaf(vb, vb, ss);
          SA[0][swz_idx(lr, lc)] = b;
        }
    __syncthreads();
    *(bf16x8*)(Xw + tXo + t * 8)        = *(const bf16x8*)(&SA[0][t * 8]);
    *(bf16x8*)(Xw + tXo + 2048 + t * 8) = *(const bf16x8*)(&SA[0][2048 + t * 8]);
    #pragma unroll
    for (int o = 32; o > 0; o >>= 1) ss += __shfl_xor(ss, o, 64);
    if (lane == 0) atomicAdd(&norm2[lev * 8 + u], ss);
  }
}

// ---------------------------------------------------------------------------
// Merged finalize + Yi GEMM, redundancy-free (fixes r11): grid (m=8, row=16)
// = 128 blocks, each owns the UNIQUE (unit m, 64-row) slice. Inline rho,
// elementwise Snew (written once; coalesced reads), packed LDS image, then
// 8 col-tile MFMA passes vs WoutT k-slice [m*512, m*512+512) with split-K
// atomics. linear_block % 8 == m -> each unit's pA/pB/Si/WoutT panels stay
// XCD-local. SnewB never materialized in global memory.
// ---------------------------------------------------------------------------
__global__ __launch_bounds__(256, 2) void k_yi3(
    const float* __restrict__ pA, const float* __restrict__ pB,
    const float* __restrict__ norm2, const float* __restrict__ norm2tmp,
    const float* __restrict__ sr, const float* __restrict__ bias,
    const float* __restrict__ lr, const float* __restrict__ Si,
    const short* __restrict__ WoutT,
    float* __restrict__ outSnew, float* __restrict__ outYi){
  __shared__ __align__(16) short ssh[32768];   // 64 KB packed A-slice (64 rows x 512)
  const int m = blockIdx.x, by = blockIdx.y;
  const int t = threadIdx.x, wv = t >> 6, lane = t & 63;
  const int wr = (wv >> 1) * 32, wc = (wv & 1) * 32;
  const int fm = lane & 15, fq = lane >> 4;
  const int row0 = by * 64;
  // inline rho for unit m (Richardson second difference at j=NLEV)
  float n0 = 0.f;
  for (int i = 0; i < 64; ++i) n0 += norm2tmp[m * 64 + i];
  float L = 0.5f * logf(n0), La = 0.f, Lb = 0.f, Lc = 0.f;
  for (int j = 1; j <= NLEV; ++j){
    L = 2.f * L + 0.5f * logf(norm2[j * 8 + m]);
    if (j == NLEV - 2) La = L;
    if (j == NLEV - 1) Lb = L;
    if (j == NLEV)     Lc = L;
  }
  const float sc = sr[m] / expf((Lc - 2.f * Lb + La) * (1.f / (float)(1 << (NLEV - 2))));
  const float lm = lr[m];
  // elementwise slice (once) -> outSnew + packed LDS
  #pragma unroll 4
  for (int l = 0; l < 128; ++l){
    int idx = l * 256 + t, r = idx >> 9, c = idx & 511;
    size_t g = ((size_t)(row0 + r) * 8 + m) * 512 + c;
    float pre = pA[g] + sc * pB[g] + bias[m * 512 + c];
    float sn = (1.f - lm) * Si[g] + lm * fast_tanh(pre);
    outSnew[g] = sn;
    ssh[PK(r, c, 512)] = f2b(sn);
  }
  __syncthreads();
  const int lo = fm * 8 + fq * 128;
  const short* A0 = ssh + wr * 512 + lo;
  #pragma unroll 1
  for (int cb = 0; cb < 8; ++cb){
    const int col0 = cb * 64;
    const short* B0 = WoutT + (size_t)(col0 + wc + fm) * 4096 + m * 512 + fq * 8;
    f32x4 zz = {0.f, 0.f, 0.f, 0.f};
    f32x4 acc[2][2] = {{zz, zz}, {zz, zz}};
    mm64_d4(A0, B0, 16 * 512, 16 * 4096, 512, 32, 16, acc);
    #pragma unroll
    for (int i = 0; i < 2; ++i)
      #pragma unroll
      for (int j = 0; j < 2; ++j)
        #pragma unroll
        for (int r = 0; r < 4; ++r){
          int row = row0 + wr + i * 16 + fq * 4 + r;
          int col = col0 + wc + j * 16 + fm;
          atomicAdd(&outYi[row * 512 + col], acc[i][j][r]);
        }
  }
}

// ---------------------------------------------------------------------------
extern "C" void kernel_launch(void* const* d_in, const int* in_sizes, int n_in,
                              void* d_out, int out_size, void* d_ws, size_t ws_size,
                              hipStream_t stream) {
  const float* Xi   = (const float*)d_in[0];
  const float* Si   = (const float*)d_in[1];
  const float* Wq   = (const float*)d_in[2];
  const float* Wk   = (const float*)d_in[3];
  const float* Wv   = (const float*)d_in[4];
  const float* Wout = (const float*)d_in[5];
  const float* W    = (const float*)d_in[6];
  const float* Win  = (const float*)d_in[7];
  const float* bias = (const float*)d_in[8];
  const float* sr   = (const float*)d_in[9];
  const float* lr   = (const float*)d_in[10];

  float* ws = (float*)d_ws;
  short* Xa    = (short*)(ws + 0);         // chain ping-pong (blocked-swz), 4 MB each
  short* Xb    = (short*)(ws + 2097152);
  short* WTpP  = (short*)(ws + 4194304);   // packed bf16 W^T per unit
  short* SiB   = (short*)(ws + 5242880);   // [8192][512] bf16 (b-major, qkv)
  short* XiB   = (short*)(ws + 7340032);   // [1024][512] bf16
  short* WqT   = (short*)(ws + 7602176);   // [m][16][512] bf16
  short* WkT   = (short*)(ws + 7634944);
  short* WvT   = (short*)(ws + 7667712);
  short* WinTP = (short*)(ws + 7700480);   // packed [m]{512 rows, K=128}
  short* WoutT = (short*)(ws + 7962624);   // [512][4096] bf16
  float* Qb    = ws + 9011200;             // [1024][128] fp32
  float* Kb    = ws + 9142272;             // [B,M,N,A] fp32
  float* Vb    = ws + 10190848;
  short* UiBuP = (short*)(ws + 11239424);  // packed [m]{1024 rows, K=128}
  float* norm2 = ws + 13860864;            // 80 used (zeroed 136)
  short* SiBuP = (short*)(ws + 13861376);  // packed [m]{1024 rows, K=512}
  float* pA    = ws + 15958528;            // [1024,8,512] fp32 accA
  float* pB    = ws + 20152832;            // [1024,8,512] fp32 accB
  float* n2tmp = ws + 24347136;            // [8][64] per-tile |W|^2 partials

  float* outYi   = (float*)d_out;            // [1024,512]
  float* outSnew = (float*)d_out + 524288;   // [1024,8,512]

  // ---- merged prep (zero + converts + transposes + W-prep), one launch ----
  k_prep_all<<<3992, 256, 0, stream>>>(Si, Xi, Wq, Wk, Wv, Win, Wout, W,
                                       SiB, SiBuP, XiB, WqT, WkT, WvT, WinTP, WoutT,
                                       Xa, WTpP, outYi, norm2, n2tmp);

  // ---- spectral radius chain + piggybacked qkv (1-4) / attn (5-6) / pre (7-9) ----
  for (int lev = 1; lev <= NLEV; ++lev){
    const short* Xr = (lev & 1) ? Xa : Xb;
    short* Xw       = (lev & 1) ? Xb : Xa;
    const int extraY = (lev <= 4) ? 17 : (lev <= 6 ? 128 : 43);
    k_lev<<<dim3(8, 32 + extraY), 256, 0, stream>>>(Xr, Xw, norm2, n2tmp, lev,
                                                    SiB, XiB, WqT, WkT, WvT, Kb, Vb, Qb, UiBuP,
                                                    SiBuP, WinTP, WTpP, pA, pB);
  }

  // ---- tail: merged finalize (inline rho + Snew once) + Yi GEMM, one launch ----
  k_yi3<<<dim3(8, 16), 256, 0, stream>>>(pA, pB, norm2, n2tmp, sr, bias, lr, Si,
                                         WoutT, outSnew, outYi);
}

// Round 14
// 461.856 us; speedup vs baseline: 1.2553x; 1.0481x over previous
//
#include <hip/hip_runtime.h>
#include <hip/hip_bf16.h>

// Problem dims
#define B_ 1024
#define I_ 512
#define O_ 512
#define M_ 8
#define R_ 512
#define A_ 16
#define D_ 128   // M_*A_
#define NLEV 8   // squaring levels; rho via (L8-2L7+L6)/64 (Richardson)

using bf16 = __hip_bfloat16;
typedef __attribute__((ext_vector_type(8))) short bf16x8;
typedef __attribute__((ext_vector_type(4))) float f32x4;

__device__ __forceinline__ short f2b(float x){
  __hip_bfloat16 h = __float2bfloat16(x);
  union { __hip_bfloat16 h; short s; } u; u.h = h; return u.s;
}
__device__ __forceinline__ float s2f(short s){
  union { short s[2]; float f; } u; u.s[0] = 0; u.s[1] = s; return u.f;
}
__device__ __forceinline__ float fast_tanh(float x){
  float xx = fminf(fmaxf(x, -9.5f), 9.5f);
  float e2 = __expf(2.f * xx);
  return (e2 - 1.f) / (e2 + 1.f);
}

// Frag-packed layout: matrix [Rows][K] bf16, element (r,k) at
// (r>>4)*(16*K) + (k>>3)*128 + (r&15)*8 + (k&7): fragment load = 1KB burst.
#define PK(r, k, K) (((size_t)((r) >> 4)) * (16 * (K)) + (((k) >> 3) * 128) + (((r) & 15) * 8) + ((k) & 7))

// Blocked-swizzled tile layout for the eigen chain: per unit, 8x8 tiles of
// 64x64 bf16; tile (rt,ct) at (rt*8+ct)*4096 shorts; element (r,c) at
// swz_idx(r,c). gl_lds staging is linear; reads apply the XOR.
__device__ __forceinline__ int swz_idx(int r, int c){
  return r * 64 + (((c >> 3) ^ (r & 7)) << 3) + (c & 7);
}

__device__ __forceinline__ void gl_lds16(const short* g, short* l){
  __builtin_amdgcn_global_load_lds((const __attribute__((address_space(1))) void*)g,
                                   (__attribute__((address_space(3))) void*)l, 16, 0, 0);
}

template<int N> __device__ __forceinline__ void wait_vmcnt(){
  if constexpr (N == 0)      asm volatile("s_waitcnt vmcnt(0)" ::: "memory");
  else if constexpr (N == 4) asm volatile("s_waitcnt vmcnt(4)" ::: "memory");
  else                       asm volatile("s_waitcnt vmcnt(8)" ::: "memory");
}

// ---------------------------------------------------------------------------
// 64x64 inner loop, depth-4 named-register pipeline (r7 proven). Separate A/B
// k-strides (A may be packed/LDS, B row-major).
// ---------------------------------------------------------------------------
__device__ __forceinline__ void mm64_d4(const short* __restrict__ A0, const short* __restrict__ B0,
                                        int rOffA, int rOffB, int kStrideA, int kStrideB, int kiters,
                                        f32x4 (&acc)[2][2]){
  const short* A1 = A0 + rOffA;
  const short* B1 = B0 + rOffB;
  bf16x8 a0, a1, b0, b1, c0, c1, d0, d1, e0, e1, f0, f1, g0, g1, h0, h1;
  a0 = *(const bf16x8*)(A0); a1 = *(const bf16x8*)(A1);
  b0 = *(const bf16x8*)(B0); b1 = *(const bf16x8*)(B1);
  if (kiters > 1){
    c0 = *(const bf16x8*)(A0 + kStrideA); c1 = *(const bf16x8*)(A1 + kStrideA);
    d0 = *(const bf16x8*)(B0 + kStrideB); d1 = *(const bf16x8*)(B1 + kStrideB);
  }
  if (kiters > 2){
    e0 = *(const bf16x8*)(A0 + 2 * kStrideA); e1 = *(const bf16x8*)(A1 + 2 * kStrideA);
    f0 = *(const bf16x8*)(B0 + 2 * kStrideB); f1 = *(const bf16x8*)(B1 + 2 * kStrideB);
  }
  if (kiters > 3){
    g0 = *(const bf16x8*)(A0 + 3 * kStrideA); g1 = *(const bf16x8*)(A1 + 3 * kStrideA);
    h0 = *(const bf16x8*)(B0 + 3 * kStrideB); h1 = *(const bf16x8*)(B1 + 3 * kStrideB);
  }
  for (int kk = 0; kk < kiters; ++kk){
    bf16x8 n0, n1, m0, m1;
    if (kk + 4 < kiters){
      n0 = *(const bf16x8*)(A0 + (size_t)(kk + 4) * kStrideA);
      n1 = *(const bf16x8*)(A1 + (size_t)(kk + 4) * kStrideA);
      m0 = *(const bf16x8*)(B0 + (size_t)(kk + 4) * kStrideB);
      m1 = *(const bf16x8*)(B1 + (size_t)(kk + 4) * kStrideB);
    }
    acc[0][0] = __builtin_amdgcn_mfma_f32_16x16x32_bf16(a0, b0, acc[0][0], 0, 0, 0);
    acc[0][1] = __builtin_amdgcn_mfma_f32_16x16x32_bf16(a0, b1, acc[0][1], 0, 0, 0);
    acc[1][0] = __builtin_amdgcn_mfma_f32_16x16x32_bf16(a1, b0, acc[1][0], 0, 0, 0);
    acc[1][1] = __builtin_amdgcn_mfma_f32_16x16x32_bf16(a1, b1, acc[1][1], 0, 0, 0);
    a0 = c0; a1 = c1; b0 = d0; b1 = d1;
    c0 = e0; c1 = e1; d0 = f0; d1 = f1;
    e0 = g0; e1 = g1; f0 = h0; f1 = h1;
    g0 = n0; g1 = n1; h0 = m0; h1 = m1;
  }
}

// ---------------------------------------------------------------------------
// Merged prep kernel: ALL independent converts incl. W-prep.
//   bid 0..511     : zero outYi (bid 0 also zeros norm2 block)
//   bid 512..2815  : cvt (Si->SiB row-major + SiBuP packed ; Xi->XiB)
//   bid 2816..2839 : Wq/Wk/Wv transpose
//   bid 2840..2967 : Win transpose -> WinTP packed
//   bid 2968..3479 : Wout transpose
//   bid 3480..3991 : W -> X0 (blocked-swz) + WTpP packed + norm2tmp[u*64+tile]
// ---------------------------------------------------------------------------
__global__ __launch_bounds__(256) void k_prep_all(
    const float* __restrict__ Si, const float* __restrict__ Xi,
    const float* __restrict__ Wq, const float* __restrict__ Wk, const float* __restrict__ Wv,
    const float* __restrict__ Win, const float* __restrict__ Wout, const float* __restrict__ W,
    short* __restrict__ SiB, short* __restrict__ SiBuP, short* __restrict__ XiB,
    short* __restrict__ WqT, short* __restrict__ WkT, short* __restrict__ WvT,
    short* __restrict__ WinTP, short* __restrict__ WoutT,
    short* __restrict__ X, short* __restrict__ WTpP,
    float* __restrict__ outYi, float* __restrict__ norm2, float* __restrict__ norm2tmp){
  __shared__ short sh[16 * 520];
  const int bid = blockIdx.x, t = threadIdx.x;
  if (bid < 512){
    if (bid == 0){ for (int i = t; i < 136; i += 256) norm2[i] = 0.f; }
    #pragma unroll
    for (int e = 0; e < 4; ++e) outYi[bid * 1024 + e * 256 + t] = 0.f;
  } else if (bid < 2816){
    const int bb0 = bid - 512;
    #pragma unroll
    for (int e = 0; e < 8; ++e){
      int idx = bb0 * 2048 + e * 256 + t;
      if (idx < 4194304){
        short b = f2b(Si[idx]);
        SiB[idx] = b;
        int bb = idx >> 12, mm = (idx >> 9) & 7, cc = idx & 511;
        SiBuP[((size_t)mm << 19) + PK(bb, cc, 512)] = b;
      } else XiB[idx - 4194304] = f2b(Xi[idx - 4194304]);
    }
  } else if (bid < 2840){
    const int i = bid - 2816, which = i / 8, m = i % 8;
    const float* src = (which == 0) ? Wq : (which == 1) ? Wk : Wv;
    short* dst = (which == 0) ? WqT : (which == 1) ? WkT : WvT;
    src += (size_t)m * 8192; dst += (size_t)m * 8192;
    #pragma unroll
    for (int l = 0; l < 32; ++l){
      int idx = l * 256 + t, ii = idx >> 4, a = idx & 15;
      sh[a * 520 + ii] = f2b(src[idx]);
    }
    __syncthreads();
    #pragma unroll
    for (int l = 0; l < 32; ++l){
      int idx = l * 256 + t, a = idx >> 9, ii = idx & 511;
      dst[a * 512 + ii] = sh[a * 520 + ii];
    }
  } else if (bid < 2968){
    // Win [m][128][512] fp32 -> WinTP packed [m]{rows=512(R), K=128(D)}
    const int i = bid - 2840;
    const int x = i & 7, y = (i >> 3) & 1, z = i >> 4;
    const float* src = Win + (size_t)z * 65536;
    const int c0 = x * 64, r0 = y * 64;
    #pragma unroll
    for (int l = 0; l < 16; ++l){
      int idx = l * 256 + t, r = idx >> 6, c = idx & 63;
      sh[r * 66 + c] = f2b(src[(size_t)(r0 + r) * 512 + c0 + c]);
    }
    __syncthreads();
    #pragma unroll
    for (int l = 0; l < 16; ++l){
      int idx = l * 256 + t, r = idx >> 6, c = idx & 63;
      int R2 = c0 + r, K2 = r0 + c;
      WinTP[(size_t)z * 65536 + PK(R2, K2, 128)] = sh[c * 66 + r];
    }
  } else if (bid < 3480){
    const int i = bid - 2968;
    const int x = i & 7, y = i >> 3;
    const int c0 = x * 64, r0 = y * 64;
    #pragma unroll
    for (int l = 0; l < 16; ++l){
      int idx = l * 256 + t, r = idx >> 6, c = idx & 63;
      sh[r * 66 + c] = f2b(Wout[(size_t)(r0 + r) * 512 + c0 + c]);
    }
    __syncthreads();
    #pragma unroll
    for (int l = 0; l < 16; ++l){
      int idx = l * 256 + t, r = idx >> 6, c = idx & 63;
      WoutT[(size_t)(c0 + r) * 4096 + r0 + c] = sh[c * 66 + r];
    }
  } else {
    // W-prep: X0 blocked-swz + WTpP packed + norm2tmp partial
    const int i = bid - 3480, u = i >> 6, tile = i & 63;
    const int rt = tile >> 3, ct = tile & 7;
    const int row0 = rt * 64, col0 = ct * 64;
    const size_t off = (size_t)u * (R_ * R_);
    const size_t tXo = off + (size_t)(rt * 8 + ct) * 4096;
    const int lane = t & 63, wvv = t >> 6;
    float ss = 0.f;
    #pragma unroll
    for (int l = 0; l < 16; ++l){
      int idx = l * 256 + t, r = idx >> 6, c = idx & 63;
      short b = f2b(W[off + (size_t)(row0 + r) * R_ + col0 + c]);
      float vb = s2f(b);
      ss = fmaf(vb, vb, ss);
      X[tXo + swz_idx(r, c)] = b;
      sh[r * 66 + c] = b;
    }
    __syncthreads();
    #pragma unroll
    for (int l = 0; l < 16; ++l){
      int idx = l * 256 + t, r = idx >> 6, c = idx & 63;
      int R2 = col0 + r, K2 = row0 + c;
      WTpP[off + PK(R2, K2, 512)] = sh[c * 66 + r];
    }
    #pragma unroll
    for (int o = 32; o > 0; o >>= 1) ss += __shfl_xor(ss, o, 64);
    __syncthreads();
    float* rf = (float*)sh;
    if (lane == 0) rf[wvv] = ss;
    __syncthreads();
    if (t == 0) norm2tmp[u * 64 + tile] = rf[0] + rf[1] + rf[2] + rf[3];
  }
}

// ---------------------------------------------------------------------------
// Chain level + piggybacked main-pipeline work.
//   yy < 32            : chain — TWO 64x64 tiles per block (yy, yy+32)
//   yy >= 32, lev 1..4 : qkv piggyback (e in [0,136))
//   yy >= 32, lev 5..6 : attn piggyback (e in [0,1024))
//   yy >= 32, lev 7..8 : pre-GEMM piggyback (512 jobs/level, disjoint)
// ---------------------------------------------------------------------------
__global__ __launch_bounds__(256, 3) void k_lev(
    const short* __restrict__ Xr, short* __restrict__ Xw,
    float* __restrict__ norm2, const float* __restrict__ norm2tmp, const int lev,
    const short* __restrict__ SiB, const short* __restrict__ XiB,
    const short* __restrict__ WqT, const short* __restrict__ WkT, const short* __restrict__ WvT,
    float* __restrict__ Kb, float* __restrict__ Vb, float* __restrict__ Qb,
    short* __restrict__ UiBuP,
    const short* __restrict__ SiBuP, const short* __restrict__ WinTP, const short* __restrict__ WTpP,
    float* __restrict__ pA, float* __restrict__ pB){
  __shared__ __align__(16) short SA[3][4096];
  __shared__ __align__(16) short SB[3][4096];
  const int u = blockIdx.x, yy = blockIdx.y;
  const int t = threadIdx.x, wv = t >> 6, lane = t & 63;
  const int wr = (wv >> 1) * 32, wc = (wv & 1) * 32;
  const int fm = lane & 15, fq = lane >> 4;

  if (yy >= 32){
    const int e = (yy - 32) * 8 + u;
    if (lev <= 4){
      // ---- qkv piggyback ----
      int z, x, yq;
      if (e < 64)       { z = 0; x = e & 1;         yq = (e >> 1)         + (lev - 1) * 32; }
      else if (e < 128) { z = 1; x = (e - 64) & 1;  yq = ((e - 64) >> 1)  + (lev - 1) * 32; }
      else              { z = 2; x = (e - 128) & 1; yq = ((e - 128) >> 1) + (lev - 1) * 4;  }
      const int ko = fq * 8;
      const int row0 = yq * 64, col0 = x * 64;
      const short* Abase = (z == 2) ? XiB : SiB;
      const short* Bbase = (z == 0) ? WkT : (z == 1) ? WvT : WqT;
      const short* A0 = Abase + (size_t)(row0 + wr + fm) * 512 + ko;
      const short* B0 = Bbase + (size_t)(col0 + wc + fm) * 512 + ko;
      f32x4 zz = {0.f, 0.f, 0.f, 0.f};
      f32x4 acc[2][2] = {{zz, zz}, {zz, zz}};
      mm64_d4(A0, B0, 16 * 512, 16 * 512, 32, 32, 16, acc);
      float* dst = (z == 0) ? Kb : (z == 1) ? Vb : Qb;
      #pragma unroll
      for (int i = 0; i < 2; ++i)
        #pragma unroll
        for (int j = 0; j < 2; ++j)
          #pragma unroll
          for (int r = 0; r < 4; ++r){
            int row = row0 + wr + i * 16 + fq * 4 + r;
            int col = col0 + wc + j * 16 + fm;
            float v = acc[i][j][r];
            if (z == 2) dst[row * 128 + col] = v;
            else {
              int b = row >> 3, n = row & 7, mc = col >> 4, a = col & 15;
              dst[b * 1024 + mc * 128 + n * 16 + a] = v;
            }
          }
    } else if (lev <= 6){
      // ---- attn piggyback (one wave per (b,m)) ----
      float* fsh = (float*)&SA[0][0];
      float* sQ = fsh, *sK = fsh + 512, *sV = fsh + 1024, *sAa = fsh + 1536;
      const int wib = wv;
      const int w = (e + (lev - 5) * 1024) * 4 + wib;
      const int b = w >> 3, m = w & 7;
      for (int e2 = lane; e2 < 128; e2 += 64){
        sQ[wib * 128 + e2] = Qb[b * 128 + e2];
        sK[wib * 128 + e2] = Kb[b * 1024 + m * 128 + e2];
        sV[wib * 128 + e2] = Vb[b * 1024 + m * 128 + e2];
      }
      __syncthreads();
      const int q = lane >> 3, n = lane & 7;
      float s = 0.f;
      #pragma unroll
      for (int a = 0; a < 16; ++a) s = fmaf(sQ[wib * 128 + q * 16 + a], sK[wib * 128 + n * 16 + a], s);
      float mx = s;
      for (int d2 = 1; d2 < 8; d2 <<= 1) mx = fmaxf(mx, __shfl_xor(mx, d2, 64));
      float p = __expf(s - mx);
      float sm = p;
      for (int d2 = 1; d2 < 8; d2 <<= 1) sm += __shfl_xor(sm, d2, 64);
      float ai = p / (sm * 11.313708498984761f);   // softmax then /sqrt(128)
      sAa[wib * 64 + q * 8 + n] = ai;
      __syncthreads();
      for (int e2 = lane; e2 < 128; e2 += 64){
        int q2 = e2 >> 4, a2 = e2 & 15;
        float acc = 0.f;
        #pragma unroll
        for (int n2 = 0; n2 < 8; ++n2) acc = fmaf(sAa[wib * 64 + q2 * 8 + n2], sV[wib * 128 + n2 * 16 + a2], acc);
        UiBuP[(size_t)m * 131072 + PK(b, e2, 128)] = f2b(acc);
      }
    } else {
      // ---- pre-GEMM piggyback: job j of 1024 over levels 7..8 (512/level) ----
      const int j = (lev - 7) * 512 + e;
      if (j >= 1024) return;
      const int m = j & 7, bz = (j >> 3) & 7, by = j >> 6;
      const int row0 = by * 64, col0 = bz * 64;
      const int lo = fm * 8 + fq * 128;
      f32x4 zz = {0.f, 0.f, 0.f, 0.f};
      f32x4 accA[2][2] = {{zz, zz}, {zz, zz}};
      f32x4 accB[2][2] = {{zz, zz}, {zz, zz}};
      {
        const short* A0 = UiBuP + (size_t)m * 131072 + (size_t)(row0 + wr) * 128 + lo;
        const short* B0 = WinTP + (size_t)m * 65536  + (size_t)(col0 + wc) * 128 + lo;
        mm64_d4(A0, B0, 16 * 128, 16 * 128, 512, 512, 4, accA);
      }
      {
        const short* A0 = SiBuP + (size_t)m * 524288 + (size_t)(row0 + wr) * 512 + lo;
        const short* B0 = WTpP  + (size_t)m * 262144 + (size_t)(col0 + wc) * 512 + lo;
        mm64_d4(A0, B0, 16 * 512, 16 * 512, 512, 512, 16, accB);
      }
      #pragma unroll
      for (int i = 0; i < 2; ++i)
        #pragma unroll
        for (int j2 = 0; j2 < 2; ++j2)
          #pragma unroll
          for (int r = 0; r < 4; ++r){
            int b = row0 + wr + i * 16 + fq * 4 + r;
            int c = col0 + wc + j2 * 16 + fm;
            size_t g = ((size_t)b * 8 + m) * 512 + c;
            pA[g] = accA[i][j2][r];
            pB[g] = accB[i][j2][r];
          }
    }
    return;
  }

  // ---- chain: two tiles per block (yy, yy+32) ----
  const size_t off = (size_t)u * (R_ * R_);
  const int swz = (fm & 7) << 4;
  int aof[2][2];
  #pragma unroll
  for (int i = 0; i < 2; ++i)
    #pragma unroll
    for (int kk = 0; kk < 2; ++kk)
      aof[i][kk] = (((wr + fm + i * 16) * 128 + kk * 64 + fq * 16) ^ swz);
  const int c0c = wc + fm,      c0h = c0c >> 3, c0l = c0c & 7;
  const int c1c = wc + 16 + fm, c1h = c1c >> 3, c1l = c1c & 7;
  float n2;
  if (lev == 1){
    n2 = 0.f;
    for (int i = 0; i < 64; ++i) n2 += norm2tmp[u * 64 + i];
  } else {
    n2 = norm2[(lev - 1) * 8 + u];
  }
  const float s2 = 1.f / n2;

  #pragma unroll 1
  for (int half = 0; half < 2; ++half){
    const int tile = yy + half * 32;
    const int rt = tile >> 3, ct = tile & 7;
    const size_t tXo = off + (size_t)(rt * 8 + ct) * 4096;
    const short* gA = Xr + off + (size_t)(rt * 8) * 4096 + t * 8;  // A tiles (rt,kt): +4096/kt
    const short* gB = Xr + off + (size_t)ct * 4096 + t * 8;        // B tiles (kt,ct): +32768/kt

    __syncthreads();   // protect LDS reuse across halves
    // prologue: stage tiles 0,1
    #pragma unroll
    for (int p = 0; p < 2; ++p){
      short* dA = &SA[p][0] + wv * 512;
      short* dB = &SB[p][0] + wv * 512;
      gl_lds16(gA + (size_t)p * 4096,         dA);
      gl_lds16(gA + (size_t)p * 4096 + 2048,  dA + 2048);
      gl_lds16(gB + (size_t)p * 32768,        dB);
      gl_lds16(gB + (size_t)p * 32768 + 2048, dB + 2048);
    }
    f32x4 zz = {0.f, 0.f, 0.f, 0.f};
    f32x4 acc[2][2] = {{zz, zz}, {zz, zz}};
    #pragma unroll
    for (int kt = 0; kt < 8; ++kt){
      if (kt < 7) wait_vmcnt<4>();
      else        wait_vmcnt<0>();
      __builtin_amdgcn_s_barrier();
      if (kt < 6){
        const int b = (kt + 2) % 3;
        short* dA = &SA[b][0] + wv * 512;
        short* dB = &SB[b][0] + wv * 512;
        gl_lds16(gA + (size_t)(kt + 2) * 4096,         dA);
        gl_lds16(gA + (size_t)(kt + 2) * 4096 + 2048,  dA + 2048);
        gl_lds16(gB + (size_t)(kt + 2) * 32768,        dB);
        gl_lds16(gB + (size_t)(kt + 2) * 32768 + 2048, dB + 2048);
      }
      const char*  Ab = (const char*)&SA[kt % 3][0];
      const short* Bb = &SB[kt % 3][0];
      #pragma unroll
      for (int kk = 0; kk < 2; ++kk){
        bf16x8 a0 = *(const bf16x8*)(Ab + aof[0][kk]);
        bf16x8 a1 = *(const bf16x8*)(Ab + aof[1][kk]);
        bf16x8 b0, b1;
        #pragma unroll
        for (int e = 0; e < 8; ++e){
          int rb = (kk * 32 + fq * 8 + e) * 64;
          b0[e] = Bb[rb + ((c0h ^ e) << 3) + c0l];
          b1[e] = Bb[rb + ((c1h ^ e) << 3) + c1l];
        }
        acc[0][0] = __builtin_amdgcn_mfma_f32_16x16x32_bf16(a0, b0, acc[0][0], 0, 0, 0);
        acc[0][1] = __builtin_amdgcn_mfma_f32_16x16x32_bf16(a0, b1, acc[0][1], 0, 0, 0);
        acc[1][0] = __builtin_amdgcn_mfma_f32_16x16x32_bf16(a1, b0, acc[1][0], 0, 0, 0);
        acc[1][1] = __builtin_amdgcn_mfma_f32_16x16x32_bf16(a1, b1, acc[1][1], 0, 0, 0);
      }
    }
    // epilogue: swizzled X' image in SA[0], linear full-line stores
    float ss = 0.f;
    #pragma unroll
    for (int i = 0; i < 2; ++i)
      #pragma unroll
      for (int j = 0; j < 2; ++j)
        #pragma unroll
        for (int r = 0; r < 4; ++r){
          int lr = wr + i * 16 + fq * 4 + r, lc = wc + j * 16 + fm;
          short b = f2b(acc[i][j][r] * s2);
          float vb = s2f(b);
          ss = fmaf(vb, vb, ss);
          SA[0][swz_idx(lr, lc)] = b;
        }
    __syncthreads();
    *(bf16x8*)(Xw + tXo + t * 8)        = *(const bf16x8*)(&SA[0][t * 8]);
    *(bf16x8*)(Xw + tXo + 2048 + t * 8) = *(const bf16x8*)(&SA[0][2048 + t * 8]);
    #pragma unroll
    for (int o = 32; o > 0; o >>= 1) ss += __shfl_xor(ss, o, 64);
    if (lane == 0) atomicAdd(&norm2[lev * 8 + u], ss);
  }
}

// ---------------------------------------------------------------------------
// Merged finalize + Yi GEMM (r13 proven, now col-split for occupancy):
// grid (m=8, row=16, z=2) = 256 blocks. Each block: inline rho, elementwise
// Snew for its (unit m, 64-row) slice (z==0 writes outSnew), packed LDS image,
// then 4 col-tiles (z*4..z*4+3) MFMA vs WoutT k-slice with split-K atomics.
// linear % 8 == m -> unit panels XCD-local; pA/pB/Si re-read (z=2) L2-served.
// ---------------------------------------------------------------------------
__global__ __launch_bounds__(256, 2) void k_yi3(
    const float* __restrict__ pA, const float* __restrict__ pB,
    const float* __restrict__ norm2, const float* __restrict__ norm2tmp,
    const float* __restrict__ sr, const float* __restrict__ bias,
    const float* __restrict__ lr, const float* __restrict__ Si,
    const short* __restrict__ WoutT,
    float* __restrict__ outSnew, float* __restrict__ outYi){
  __shared__ __align__(16) short ssh[32768];   // 64 KB packed A-slice (64 rows x 512)
  const int m = blockIdx.x, by = blockIdx.y, zc = blockIdx.z;
  const int t = threadIdx.x, wv = t >> 6, lane = t & 63;
  const int wr = (wv >> 1) * 32, wc = (wv & 1) * 32;
  const int fm = lane & 15, fq = lane >> 4;
  const int row0 = by * 64;
  // inline rho for unit m (Richardson second difference at j=NLEV)
  float n0 = 0.f;
  for (int i = 0; i < 64; ++i) n0 += norm2tmp[m * 64 + i];
  float L = 0.5f * logf(n0), La = 0.f, Lb = 0.f, Lc = 0.f;
  for (int j = 1; j <= NLEV; ++j){
    L = 2.f * L + 0.5f * logf(norm2[j * 8 + m]);
    if (j == NLEV - 2) La = L;
    if (j == NLEV - 1) Lb = L;
    if (j == NLEV)     Lc = L;
  }
  const float sc = sr[m] / expf((Lc - 2.f * Lb + La) * (1.f / (float)(1 << (NLEV - 2))));
  const float lm = lr[m];
  // elementwise slice -> (z==0) outSnew + packed LDS
  #pragma unroll 4
  for (int l = 0; l < 128; ++l){
    int idx = l * 256 + t, r = idx >> 9, c = idx & 511;
    size_t g = ((size_t)(row0 + r) * 8 + m) * 512 + c;
    float pre = pA[g] + sc * pB[g] + bias[m * 512 + c];
    float sn = (1.f - lm) * Si[g] + lm * fast_tanh(pre);
    if (zc == 0) outSnew[g] = sn;
    ssh[PK(r, c, 512)] = f2b(sn);
  }
  __syncthreads();
  const int lo = fm * 8 + fq * 128;
  const short* A0 = ssh + wr * 512 + lo;
  #pragma unroll 1
  for (int cb = zc * 4; cb < zc * 4 + 4; ++cb){
    const int col0 = cb * 64;
    const short* B0 = WoutT + (size_t)(col0 + wc + fm) * 4096 + m * 512 + fq * 8;
    f32x4 zz = {0.f, 0.f, 0.f, 0.f};
    f32x4 acc[2][2] = {{zz, zz}, {zz, zz}};
    mm64_d4(A0, B0, 16 * 512, 16 * 4096, 512, 32, 16, acc);
    #pragma unroll
    for (int i = 0; i < 2; ++i)
      #pragma unroll
      for (int j = 0; j < 2; ++j)
        #pragma unroll
        for (int r = 0; r < 4; ++r){
          int row = row0 + wr + i * 16 + fq * 4 + r;
          int col = col0 + wc + j * 16 + fm;
          atomicAdd(&outYi[row * 512 + col], acc[i][j][r]);
        }
  }
}

// ---------------------------------------------------------------------------
extern "C" void kernel_launch(void* const* d_in, const int* in_sizes, int n_in,
                              void* d_out, int out_size, void* d_ws, size_t ws_size,
                              hipStream_t stream) {
  const float* Xi   = (const float*)d_in[0];
  const float* Si   = (const float*)d_in[1];
  const float* Wq   = (const float*)d_in[2];
  const float* Wk   = (const float*)d_in[3];
  const float* Wv   = (const float*)d_in[4];
  const float* Wout = (const float*)d_in[5];
  const float* W    = (const float*)d_in[6];
  const float* Win  = (const float*)d_in[7];
  const float* bias = (const float*)d_in[8];
  const float* sr   = (const float*)d_in[9];
  const float* lr   = (const float*)d_in[10];

  float* ws = (float*)d_ws;
  short* Xa    = (short*)(ws + 0);         // chain ping-pong (blocked-swz), 4 MB each
  short* Xb    = (short*)(ws + 2097152);
  short* WTpP  = (short*)(ws + 4194304);   // packed bf16 W^T per unit
  short* SiB   = (short*)(ws + 5242880);   // [8192][512] bf16 (b-major, qkv)
  short* XiB   = (short*)(ws + 7340032);   // [1024][512] bf16
  short* WqT   = (short*)(ws + 7602176);   // [m][16][512] bf16
  short* WkT   = (short*)(ws + 7634944);
  short* WvT   = (short*)(ws + 7667712);
  short* WinTP = (short*)(ws + 7700480);   // packed [m]{512 rows, K=128}
  short* WoutT = (short*)(ws + 7962624);   // [512][4096] bf16
  float* Qb    = ws + 9011200;             // [1024][128] fp32
  float* Kb    = ws + 9142272;             // [B,M,N,A] fp32
  float* Vb    = ws + 10190848;
  short* UiBuP = (short*)(ws + 11239424);  // packed [m]{1024 rows, K=128}
  float* norm2 = ws + 13860864;            // 72 used (zeroed 136)
  short* SiBuP = (short*)(ws + 13861376);  // packed [m]{1024 rows, K=512}
  float* pA    = ws + 15958528;            // [1024,8,512] fp32 accA
  float* pB    = ws + 20152832;            // [1024,8,512] fp32 accB
  float* n2tmp = ws + 24347136;            // [8][64] per-tile |W|^2 partials

  float* outYi   = (float*)d_out;            // [1024,512]
  float* outSnew = (float*)d_out + 524288;   // [1024,8,512]

  // ---- merged prep (zero + converts + transposes + W-prep), one launch ----
  k_prep_all<<<3992, 256, 0, stream>>>(Si, Xi, Wq, Wk, Wv, Win, Wout, W,
                                       SiB, SiBuP, XiB, WqT, WkT, WvT, WinTP, WoutT,
                                       Xa, WTpP, outYi, norm2, n2tmp);

  // ---- spectral radius chain + piggybacked qkv (1-4) / attn (5-6) / pre (7-8) ----
  for (int lev = 1; lev <= NLEV; ++lev){
    const short* Xr = (lev & 1) ? Xa : Xb;
    short* Xw       = (lev & 1) ? Xb : Xa;
    const int extraY = (lev <= 4) ? 17 : (lev <= 6 ? 128 : 64);
    k_lev<<<dim3(8, 32 + extraY), 256, 0, stream>>>(Xr, Xw, norm2, n2tmp, lev,
                                                    SiB, XiB, WqT, WkT, WvT, Kb, Vb, Qb, UiBuP,
                                                    SiBuP, WinTP, WTpP, pA, pB);
  }

  // ---- tail: merged finalize (inline rho + Snew) + Yi GEMM, col-split z=2 ----
  k_yi3<<<dim3(8, 16, 2), 256, 0, stream>>>(pA, pB, norm2, n2tmp, sr, bias, lr, Si,
                                            WoutT, outSnew, outYi);
}

// Round 15
// 457.846 us; speedup vs baseline: 1.2663x; 1.0088x over previous
//
#include <hip/hip_runtime.h>
#include <hip/hip_bf16.h>

// Problem dims
#define B_ 1024
#define I_ 512
#define O_ 512
#define M_ 8
#define R_ 512
#define A_ 16
#define D_ 128   // M_*A_
#define NLEV 8   // squaring levels; rho via (L8-2L7+L6)/64 (Richardson)

using bf16 = __hip_bfloat16;
typedef __attribute__((ext_vector_type(8))) short bf16x8;
typedef __attribute__((ext_vector_type(4))) float f32x4;

__device__ __forceinline__ short f2b(float x){
  __hip_bfloat16 h = __float2bfloat16(x);
  union { __hip_bfloat16 h; short s; } u; u.h = h; return u.s;
}
__device__ __forceinline__ float s2f(short s){
  union { short s[2]; float f; } u; u.s[0] = 0; u.s[1] = s; return u.f;
}
__device__ __forceinline__ float fast_tanh(float x){
  float xx = fminf(fmaxf(x, -9.5f), 9.5f);
  float e2 = __expf(2.f * xx);
  return (e2 - 1.f) / (e2 + 1.f);
}

// Frag-packed layout: matrix [Rows][K] bf16, element (r,k) at
// (r>>4)*(16*K) + (k>>3)*128 + (r&15)*8 + (k&7): fragment load = 1KB burst.
#define PK(r, k, K) (((size_t)((r) >> 4)) * (16 * (K)) + (((k) >> 3) * 128) + (((r) & 15) * 8) + ((k) & 7))

// Blocked-swizzled tile layout for the eigen chain: per unit, 8x8 tiles of
// 64x64 bf16; tile (rt,ct) at (rt*8+ct)*4096 shorts; element (r,c) at
// swz_idx(r,c). gl_lds staging is linear; reads apply the XOR.
__device__ __forceinline__ int swz_idx(int r, int c){
  return r * 64 + (((c >> 3) ^ (r & 7)) << 3) + (c & 7);
}

__device__ __forceinline__ void gl_lds16(const short* g, short* l){
  __builtin_amdgcn_global_load_lds((const __attribute__((address_space(1))) void*)g,
                                   (__attribute__((address_space(3))) void*)l, 16, 0, 0);
}

template<int N> __device__ __forceinline__ void wait_vmcnt(){
  if constexpr (N == 0)      asm volatile("s_waitcnt vmcnt(0)" ::: "memory");
  else if constexpr (N == 4) asm volatile("s_waitcnt vmcnt(4)" ::: "memory");
  else                       asm volatile("s_waitcnt vmcnt(8)" ::: "memory");
}

// ---------------------------------------------------------------------------
// 64x64 inner loop, depth-4 named-register pipeline (r7 proven). Separate A/B
// k-strides (A may be packed/LDS, B row-major).
// ---------------------------------------------------------------------------
__device__ __forceinline__ void mm64_d4(const short* __restrict__ A0, const short* __restrict__ B0,
                                        int rOffA, int rOffB, int kStrideA, int kStrideB, int kiters,
                                        f32x4 (&acc)[2][2]){
  const short* A1 = A0 + rOffA;
  const short* B1 = B0 + rOffB;
  bf16x8 a0, a1, b0, b1, c0, c1, d0, d1, e0, e1, f0, f1, g0, g1, h0, h1;
  a0 = *(const bf16x8*)(A0); a1 = *(const bf16x8*)(A1);
  b0 = *(const bf16x8*)(B0); b1 = *(const bf16x8*)(B1);
  if (kiters > 1){
    c0 = *(const bf16x8*)(A0 + kStrideA); c1 = *(const bf16x8*)(A1 + kStrideA);
    d0 = *(const bf16x8*)(B0 + kStrideB); d1 = *(const bf16x8*)(B1 + kStrideB);
  }
  if (kiters > 2){
    e0 = *(const bf16x8*)(A0 + 2 * kStrideA); e1 = *(const bf16x8*)(A1 + 2 * kStrideA);
    f0 = *(const bf16x8*)(B0 + 2 * kStrideB); f1 = *(const bf16x8*)(B1 + 2 * kStrideB);
  }
  if (kiters > 3){
    g0 = *(const bf16x8*)(A0 + 3 * kStrideA); g1 = *(const bf16x8*)(A1 + 3 * kStrideA);
    h0 = *(const bf16x8*)(B0 + 3 * kStrideB); h1 = *(const bf16x8*)(B1 + 3 * kStrideB);
  }
  for (int kk = 0; kk < kiters; ++kk){
    bf16x8 n0, n1, m0, m1;
    if (kk + 4 < kiters){
      n0 = *(const bf16x8*)(A0 + (size_t)(kk + 4) * kStrideA);
      n1 = *(const bf16x8*)(A1 + (size_t)(kk + 4) * kStrideA);
      m0 = *(const bf16x8*)(B0 + (size_t)(kk + 4) * kStrideB);
      m1 = *(const bf16x8*)(B1 + (size_t)(kk + 4) * kStrideB);
    }
    acc[0][0] = __builtin_amdgcn_mfma_f32_16x16x32_bf16(a0, b0, acc[0][0], 0, 0, 0);
    acc[0][1] = __builtin_amdgcn_mfma_f32_16x16x32_bf16(a0, b1, acc[0][1], 0, 0, 0);
    acc[1][0] = __builtin_amdgcn_mfma_f32_16x16x32_bf16(a1, b0, acc[1][0], 0, 0, 0);
    acc[1][1] = __builtin_amdgcn_mfma_f32_16x16x32_bf16(a1, b1, acc[1][1], 0, 0, 0);
    a0 = c0; a1 = c1; b0 = d0; b1 = d1;
    c0 = e0; c1 = e1; d0 = f0; d1 = f1;
    e0 = g0; e1 = g1; f0 = h0; f1 = h1;
    g0 = n0; g1 = n1; h0 = m0; h1 = m1;
  }
}

// 16-row x 32-col per-wave variant: one A-frag stream, two B-frag streams.
__device__ __forceinline__ void mm32_d4(const short* __restrict__ A0, const short* __restrict__ B0,
                                        int rOffB, int kStrideA, int kStrideB, int kiters,
                                        f32x4 (&acc)[2]){
  const short* B1 = B0 + rOffB;
  bf16x8 a0, b0, b1, c0, d0, d1, e0, f0, f1, g0, h0, h1;
  a0 = *(const bf16x8*)(A0);
  b0 = *(const bf16x8*)(B0); b1 = *(const bf16x8*)(B1);
  if (kiters > 1){
    c0 = *(const bf16x8*)(A0 + kStrideA);
    d0 = *(const bf16x8*)(B0 + kStrideB); d1 = *(const bf16x8*)(B1 + kStrideB);
  }
  if (kiters > 2){
    e0 = *(const bf16x8*)(A0 + 2 * kStrideA);
    f0 = *(const bf16x8*)(B0 + 2 * kStrideB); f1 = *(const bf16x8*)(B1 + 2 * kStrideB);
  }
  if (kiters > 3){
    g0 = *(const bf16x8*)(A0 + 3 * kStrideA);
    h0 = *(const bf16x8*)(B0 + 3 * kStrideB); h1 = *(const bf16x8*)(B1 + 3 * kStrideB);
  }
  for (int kk = 0; kk < kiters; ++kk){
    bf16x8 n0, m0, m1;
    if (kk + 4 < kiters){
      n0 = *(const bf16x8*)(A0 + (size_t)(kk + 4) * kStrideA);
      m0 = *(const bf16x8*)(B0 + (size_t)(kk + 4) * kStrideB);
      m1 = *(const bf16x8*)(B1 + (size_t)(kk + 4) * kStrideB);
    }
    acc[0] = __builtin_amdgcn_mfma_f32_16x16x32_bf16(a0, b0, acc[0], 0, 0, 0);
    acc[1] = __builtin_amdgcn_mfma_f32_16x16x32_bf16(a0, b1, acc[1], 0, 0, 0);
    a0 = c0; b0 = d0; b1 = d1;
    c0 = e0; d0 = f0; d1 = f1;
    e0 = g0; f0 = h0; f1 = h1;
    g0 = n0; h0 = m0; h1 = m1;
  }
}

// ---------------------------------------------------------------------------
// Merged prep kernel: ALL independent converts incl. W-prep.
//   bid 0..511     : zero outYi (bid 0 also zeros norm2 block)
//   bid 512..2815  : cvt (Si->SiB row-major + SiBuP packed ; Xi->XiB)
//   bid 2816..2839 : Wq/Wk/Wv transpose
//   bid 2840..2967 : Win transpose -> WinTP packed
//   bid 2968..3479 : Wout transpose
//   bid 3480..3991 : W -> X0 (blocked-swz) + WTpP packed + norm2tmp[u*64+tile]
// ---------------------------------------------------------------------------
__global__ __launch_bounds__(256) void k_prep_all(
    const float* __restrict__ Si, const float* __restrict__ Xi,
    const float* __restrict__ Wq, const float* __restrict__ Wk, const float* __restrict__ Wv,
    const float* __restrict__ Win, const float* __restrict__ Wout, const float* __restrict__ W,
    short* __restrict__ SiB, short* __restrict__ SiBuP, short* __restrict__ XiB,
    short* __restrict__ WqT, short* __restrict__ WkT, short* __restrict__ WvT,
    short* __restrict__ WinTP, short* __restrict__ WoutT,
    short* __restrict__ X, short* __restrict__ WTpP,
    float* __restrict__ outYi, float* __restrict__ norm2, float* __restrict__ norm2tmp){
  __shared__ short sh[16 * 520];
  const int bid = blockIdx.x, t = threadIdx.x;
  if (bid < 512){
    if (bid == 0){ for (int i = t; i < 136; i += 256) norm2[i] = 0.f; }
    #pragma unroll
    for (int e = 0; e < 4; ++e) outYi[bid * 1024 + e * 256 + t] = 0.f;
  } else if (bid < 2816){
    const int bb0 = bid - 512;
    #pragma unroll
    for (int e = 0; e < 8; ++e){
      int idx = bb0 * 2048 + e * 256 + t;
      if (idx < 4194304){
        short b = f2b(Si[idx]);
        SiB[idx] = b;
        int bb = idx >> 12, mm = (idx >> 9) & 7, cc = idx & 511;
        SiBuP[((size_t)mm << 19) + PK(bb, cc, 512)] = b;
      } else XiB[idx - 4194304] = f2b(Xi[idx - 4194304]);
    }
  } else if (bid < 2840){
    const int i = bid - 2816, which = i / 8, m = i % 8;
    const float* src = (which == 0) ? Wq : (which == 1) ? Wk : Wv;
    short* dst = (which == 0) ? WqT : (which == 1) ? WkT : WvT;
    src += (size_t)m * 8192; dst += (size_t)m * 8192;
    #pragma unroll
    for (int l = 0; l < 32; ++l){
      int idx = l * 256 + t, ii = idx >> 4, a = idx & 15;
      sh[a * 520 + ii] = f2b(src[idx]);
    }
    __syncthreads();
    #pragma unroll
    for (int l = 0; l < 32; ++l){
      int idx = l * 256 + t, a = idx >> 9, ii = idx & 511;
      dst[a * 512 + ii] = sh[a * 520 + ii];
    }
  } else if (bid < 2968){
    // Win [m][128][512] fp32 -> WinTP packed [m]{rows=512(R), K=128(D)}
    const int i = bid - 2840;
    const int x = i & 7, y = (i >> 3) & 1, z = i >> 4;
    const float* src = Win + (size_t)z * 65536;
    const int c0 = x * 64, r0 = y * 64;
    #pragma unroll
    for (int l = 0; l < 16; ++l){
      int idx = l * 256 + t, r = idx >> 6, c = idx & 63;
      sh[r * 66 + c] = f2b(src[(size_t)(r0 + r) * 512 + c0 + c]);
    }
    __syncthreads();
    #pragma unroll
    for (int l = 0; l < 16; ++l){
      int idx = l * 256 + t, r = idx >> 6, c = idx & 63;
      int R2 = c0 + r, K2 = r0 + c;
      WinTP[(size_t)z * 65536 + PK(R2, K2, 128)] = sh[c * 66 + r];
    }
  } else if (bid < 3480){
    const int i = bid - 2968;
    const int x = i & 7, y = i >> 3;
    const int c0 = x * 64, r0 = y * 64;
    #pragma unroll
    for (int l = 0; l < 16; ++l){
      int idx = l * 256 + t, r = idx >> 6, c = idx & 63;
      sh[r * 66 + c] = f2b(Wout[(size_t)(r0 + r) * 512 + c0 + c]);
    }
    __syncthreads();
    #pragma unroll
    for (int l = 0; l < 16; ++l){
      int idx = l * 256 + t, r = idx >> 6, c = idx & 63;
      WoutT[(size_t)(c0 + r) * 4096 + r0 + c] = sh[c * 66 + r];
    }
  } else {
    // W-prep: X0 blocked-swz + WTpP packed + norm2tmp partial
    const int i = bid - 3480, u = i >> 6, tile = i & 63;
    const int rt = tile >> 3, ct = tile & 7;
    const int row0 = rt * 64, col0 = ct * 64;
    const size_t off = (size_t)u * (R_ * R_);
    const size_t tXo = off + (size_t)(rt * 8 + ct) * 4096;
    const int lane = t & 63, wvv = t >> 6;
    float ss = 0.f;
    #pragma unroll
    for (int l = 0; l < 16; ++l){
      int idx = l * 256 + t, r = idx >> 6, c = idx & 63;
      short b = f2b(W[off + (size_t)(row0 + r) * R_ + col0 + c]);
      float vb = s2f(b);
      ss = fmaf(vb, vb, ss);
      X[tXo + swz_idx(r, c)] = b;
      sh[r * 66 + c] = b;
    }
    __syncthreads();
    #pragma unroll
    for (int l = 0; l < 16; ++l){
      int idx = l * 256 + t, r = idx >> 6, c = idx & 63;
      int R2 = col0 + r, K2 = row0 + c;
      WTpP[off + PK(R2, K2, 512)] = sh[c * 66 + r];
    }
    #pragma unroll
    for (int o = 32; o > 0; o >>= 1) ss += __shfl_xor(ss, o, 64);
    __syncthreads();
    float* rf = (float*)sh;
    if (lane == 0) rf[wvv] = ss;
    __syncthreads();
    if (t == 0) norm2tmp[u * 64 + tile] = rf[0] + rf[1] + rf[2] + rf[3];
  }
}

// ---------------------------------------------------------------------------
// Chain level + piggybacked main-pipeline work.
//   yy < 32            : chain — TWO 64x64 tiles per block (yy, yy+32)
//   yy >= 32, lev 1..4 : qkv piggyback (e in [0,136))
//   yy >= 32, lev 5..6 : attn piggyback (e in [0,1024))
//   yy >= 32, lev 7..8 : pre-GEMM piggyback (512 jobs/level, disjoint)
// ---------------------------------------------------------------------------
__global__ __launch_bounds__(256, 3) void k_lev(
    const short* __restrict__ Xr, short* __restrict__ Xw,
    float* __restrict__ norm2, const float* __restrict__ norm2tmp, const int lev,
    const short* __restrict__ SiB, const short* __restrict__ XiB,
    const short* __restrict__ WqT, const short* __restrict__ WkT, const short* __restrict__ WvT,
    float* __restrict__ Kb, float* __restrict__ Vb, float* __restrict__ Qb,
    short* __restrict__ UiBuP,
    const short* __restrict__ SiBuP, const short* __restrict__ WinTP, const short* __restrict__ WTpP,
    float* __restrict__ pA, float* __restrict__ pB){
  __shared__ __align__(16) short SA[3][4096];
  __shared__ __align__(16) short SB[3][4096];
  const int u = blockIdx.x, yy = blockIdx.y;
  const int t = threadIdx.x, wv = t >> 6, lane = t & 63;
  const int wr = (wv >> 1) * 32, wc = (wv & 1) * 32;
  const int fm = lane & 15, fq = lane >> 4;

  if (yy >= 32){
    const int e = (yy - 32) * 8 + u;
    if (lev <= 4){
      // ---- qkv piggyback ----
      int z, x, yq;
      if (e < 64)       { z = 0; x = e & 1;         yq = (e >> 1)         + (lev - 1) * 32; }
      else if (e < 128) { z = 1; x = (e - 64) & 1;  yq = ((e - 64) >> 1)  + (lev - 1) * 32; }
      else              { z = 2; x = (e - 128) & 1; yq = ((e - 128) >> 1) + (lev - 1) * 4;  }
      const int ko = fq * 8;
      const int row0 = yq * 64, col0 = x * 64;
      const short* Abase = (z == 2) ? XiB : SiB;
      const short* Bbase = (z == 0) ? WkT : (z == 1) ? WvT : WqT;
      const short* A0 = Abase + (size_t)(row0 + wr + fm) * 512 + ko;
      const short* B0 = Bbase + (size_t)(col0 + wc + fm) * 512 + ko;
      f32x4 zz = {0.f, 0.f, 0.f, 0.f};
      f32x4 acc[2][2] = {{zz, zz}, {zz, zz}};
      mm64_d4(A0, B0, 16 * 512, 16 * 512, 32, 32, 16, acc);
      float* dst = (z == 0) ? Kb : (z == 1) ? Vb : Qb;
      #pragma unroll
      for (int i = 0; i < 2; ++i)
        #pragma unroll
        for (int j = 0; j < 2; ++j)
          #pragma unroll
          for (int r = 0; r < 4; ++r){
            int row = row0 + wr + i * 16 + fq * 4 + r;
            int col = col0 + wc + j * 16 + fm;
            float v = acc[i][j][r];
            if (z == 2) dst[row * 128 + col] = v;
            else {
              int b = row >> 3, n = row & 7, mc = col >> 4, a = col & 15;
              dst[b * 1024 + mc * 128 + n * 16 + a] = v;
            }
          }
    } else if (lev <= 6){
      // ---- attn piggyback (one wave per (b,m)) ----
      float* fsh = (float*)&SA[0][0];
      float* sQ = fsh, *sK = fsh + 512, *sV = fsh + 1024, *sAa = fsh + 1536;
      const int wib = wv;
      const int w = (e + (lev - 5) * 1024) * 4 + wib;
      const int b = w >> 3, m = w & 7;
      for (int e2 = lane; e2 < 128; e2 += 64){
        sQ[wib * 128 + e2] = Qb[b * 128 + e2];
        sK[wib * 128 + e2] = Kb[b * 1024 + m * 128 + e2];
        sV[wib * 128 + e2] = Vb[b * 1024 + m * 128 + e2];
      }
      __syncthreads();
      const int q = lane >> 3, n = lane & 7;
      float s = 0.f;
      #pragma unroll
      for (int a = 0; a < 16; ++a) s = fmaf(sQ[wib * 128 + q * 16 + a], sK[wib * 128 + n * 16 + a], s);
      float mx = s;
      for (int d2 = 1; d2 < 8; d2 <<= 1) mx = fmaxf(mx, __shfl_xor(mx, d2, 64));
      float p = __expf(s - mx);
      float sm = p;
      for (int d2 = 1; d2 < 8; d2 <<= 1) sm += __shfl_xor(sm, d2, 64);
      float ai = p / (sm * 11.313708498984761f);   // softmax then /sqrt(128)
      sAa[wib * 64 + q * 8 + n] = ai;
      __syncthreads();
      for (int e2 = lane; e2 < 128; e2 += 64){
        int q2 = e2 >> 4, a2 = e2 & 15;
        float acc = 0.f;
        #pragma unroll
        for (int n2 = 0; n2 < 8; ++n2) acc = fmaf(sAa[wib * 64 + q2 * 8 + n2], sV[wib * 128 + n2 * 16 + a2], acc);
        UiBuP[(size_t)m * 131072 + PK(b, e2, 128)] = f2b(acc);
      }
    } else {
      // ---- pre-GEMM piggyback: job j of 1024 over levels 7..8 (512/level) ----
      const int j = (lev - 7) * 512 + e;
      if (j >= 1024) return;
      const int m = j & 7, bz = (j >> 3) & 7, by = j >> 6;
      const int row0 = by * 64, col0 = bz * 64;
      const int lo = fm * 8 + fq * 128;
      f32x4 zz = {0.f, 0.f, 0.f, 0.f};
      f32x4 accA[2][2] = {{zz, zz}, {zz, zz}};
      f32x4 accB[2][2] = {{zz, zz}, {zz, zz}};
      {
        const short* A0 = UiBuP + (size_t)m * 131072 + (size_t)(row0 + wr) * 128 + lo;
        const short* B0 = WinTP + (size_t)m * 65536  + (size_t)(col0 + wc) * 128 + lo;
        mm64_d4(A0, B0, 16 * 128, 16 * 128, 512, 512, 4, accA);
      }
      {
        const short* A0 = SiBuP + (size_t)m * 524288 + (size_t)(row0 + wr) * 512 + lo;
        const short* B0 = WTpP  + (size_t)m * 262144 + (size_t)(col0 + wc) * 512 + lo;
        mm64_d4(A0, B0, 16 * 512, 16 * 512, 512, 512, 16, accB);
      }
      #pragma unroll
      for (int i = 0; i < 2; ++i)
        #pragma unroll
        for (int j2 = 0; j2 < 2; ++j2)
          #pragma unroll
          for (int r = 0; r < 4; ++r){
            int b = row0 + wr + i * 16 + fq * 4 + r;
            int c = col0 + wc + j2 * 16 + fm;
            size_t g = ((size_t)b * 8 + m) * 512 + c;
            pA[g] = accA[i][j2][r];
            pB[g] = accB[i][j2][r];
          }
    }
    return;
  }

  // ---- chain: two tiles per block (yy, yy+32) ----
  const size_t off = (size_t)u * (R_ * R_);
  const int swz = (fm & 7) << 4;
  int aof[2][2];
  #pragma unroll
  for (int i = 0; i < 2; ++i)
    #pragma unroll
    for (int kk = 0; kk < 2; ++kk)
      aof[i][kk] = (((wr + fm + i * 16) * 128 + kk * 64 + fq * 16) ^ swz);
  const int c0c = wc + fm,      c0h = c0c >> 3, c0l = c0c & 7;
  const int c1c = wc + 16 + fm, c1h = c1c >> 3, c1l = c1c & 7;
  float n2;
  if (lev == 1){
    n2 = 0.f;
    for (int i = 0; i < 64; ++i) n2 += norm2tmp[u * 64 + i];
  } else {
    n2 = norm2[(lev - 1) * 8 + u];
  }
  const float s2 = 1.f / n2;

  #pragma unroll 1
  for (int half = 0; half < 2; ++half){
    const int tile = yy + half * 32;
    const int rt = tile >> 3, ct = tile & 7;
    const size_t tXo = off + (size_t)(rt * 8 + ct) * 4096;
    const short* gA = Xr + off + (size_t)(rt * 8) * 4096 + t * 8;  // A tiles (rt,kt): +4096/kt
    const short* gB = Xr + off + (size_t)ct * 4096 + t * 8;        // B tiles (kt,ct): +32768/kt

    __syncthreads();   // protect LDS reuse across halves
    // prologue: stage tiles 0,1
    #pragma unroll
    for (int p = 0; p < 2; ++p){
      short* dA = &SA[p][0] + wv * 512;
      short* dB = &SB[p][0] + wv * 512;
      gl_lds16(gA + (size_t)p * 4096,         dA);
      gl_lds16(gA + (size_t)p * 4096 + 2048,  dA + 2048);
      gl_lds16(gB + (size_t)p * 32768,        dB);
      gl_lds16(gB + (size_t)p * 32768 + 2048, dB + 2048);
    }
    f32x4 zz = {0.f, 0.f, 0.f, 0.f};
    f32x4 acc[2][2] = {{zz, zz}, {zz, zz}};
    #pragma unroll
    for (int kt = 0; kt < 8; ++kt){
      if (kt < 7) wait_vmcnt<4>();
      else        wait_vmcnt<0>();
      __builtin_amdgcn_s_barrier();
      if (kt < 6){
        const int b = (kt + 2) % 3;
        short* dA = &SA[b][0] + wv * 512;
        short* dB = &SB[b][0] + wv * 512;
        gl_lds16(gA + (size_t)(kt + 2) * 4096,         dA);
        gl_lds16(gA + (size_t)(kt + 2) * 4096 + 2048,  dA + 2048);
        gl_lds16(gB + (size_t)(kt + 2) * 32768,        dB);
        gl_lds16(gB + (size_t)(kt + 2) * 32768 + 2048, dB + 2048);
      }
      const char*  Ab = (const char*)&SA[kt % 3][0];
      const short* Bb = &SB[kt % 3][0];
      #pragma unroll
      for (int kk = 0; kk < 2; ++kk){
        bf16x8 a0 = *(const bf16x8*)(Ab + aof[0][kk]);
        bf16x8 a1 = *(const bf16x8*)(Ab + aof[1][kk]);
        bf16x8 b0, b1;
        #pragma unroll
        for (int e = 0; e < 8; ++e){
          int rb = (kk * 32 + fq * 8 + e) * 64;
          b0[e] = Bb[rb + ((c0h ^ e) << 3) + c0l];
          b1[e] = Bb[rb + ((c1h ^ e) << 3) + c1l];
        }
        acc[0][0] = __builtin_amdgcn_mfma_f32_16x16x32_bf16(a0, b0, acc[0][0], 0, 0, 0);
        acc[0][1] = __builtin_amdgcn_mfma_f32_16x16x32_bf16(a0, b1, acc[0][1], 0, 0, 0);
        acc[1][0] = __builtin_amdgcn_mfma_f32_16x16x32_bf16(a1, b0, acc[1][0], 0, 0, 0);
        acc[1][1] = __builtin_amdgcn_mfma_f32_16x16x32_bf16(a1, b1, acc[1][1], 0, 0, 0);
      }
    }
    // epilogue: swizzled X' image in SA[0], linear full-line stores
    float ss = 0.f;
    #pragma unroll
    for (int i = 0; i < 2; ++i)
      #pragma unroll
      for (int j = 0; j < 2; ++j)
        #pragma unroll
        for (int r = 0; r < 4; ++r){
          int lr = wr + i * 16 + fq * 4 + r, lc = wc + j * 16 + fm;
          short b = f2b(acc[i][j][r] * s2);
          float vb = s2f(b);
          ss = fmaf(vb, vb, ss);
          SA[0][swz_idx(lr, lc)] = b;
        }
    __syncthreads();
    *(bf16x8*)(Xw + tXo + t * 8)        = *(const bf16x8*)(&SA[0][t * 8]);
    *(bf16x8*)(Xw + tXo + 2048 + t * 8) = *(const bf16x8*)(&SA[0][2048 + t * 8]);
    #pragma unroll
    for (int o = 32; o > 0; o >>= 1) ss += __shfl_xor(ss, o, 64);
    if (lane == 0) atomicAdd(&norm2[lev * 8 + u], ss);
  }
}

// ---------------------------------------------------------------------------
// Merged finalize + Yi GEMM, 32-row partition (no duplication): grid
// (m=8, row=32) = 256 blocks, each owns the UNIQUE (unit m, 32-row) slice.
// Inline rho, elementwise Snew once, 32KB packed LDS image (3 blocks/CU),
// then 8 col-tiles: per wave 16x32 output via mm32_d4, split-K atomics.
// linear % 8 == m -> unit panels XCD-local.
// ---------------------------------------------------------------------------
__global__ __launch_bounds__(256, 3) void k_yi4(
    const float* __restrict__ pA, const float* __restrict__ pB,
    const float* __restrict__ norm2, const float* __restrict__ norm2tmp,
    const float* __restrict__ sr, const float* __restrict__ bias,
    const float* __restrict__ lr, const float* __restrict__ Si,
    const short* __restrict__ WoutT,
    float* __restrict__ outSnew, float* __restrict__ outYi){
  __shared__ __align__(16) short ssh[16384];   // 32 KB packed A-slice (32 rows x 512)
  const int m = blockIdx.x, by = blockIdx.y;
  const int t = threadIdx.x, wv = t >> 6, lane = t & 63;
  const int rh = wv >> 1, ch = wv & 1;          // wave -> 16-row half, 32-col half
  const int fm = lane & 15, fq = lane >> 4;
  const int row0 = by * 32;
  // inline rho for unit m (Richardson second difference at j=NLEV)
  float n0 = 0.f;
  for (int i = 0; i < 64; ++i) n0 += norm2tmp[m * 64 + i];
  float L = 0.5f * logf(n0), La = 0.f, Lb = 0.f, Lc = 0.f;
  for (int j = 1; j <= NLEV; ++j){
    L = 2.f * L + 0.5f * logf(norm2[j * 8 + m]);
    if (j == NLEV - 2) La = L;
    if (j == NLEV - 1) Lb = L;
    if (j == NLEV)     Lc = L;
  }
  const float sc = sr[m] / expf((Lc - 2.f * Lb + La) * (1.f / (float)(1 << (NLEV - 2))));
  const float lm = lr[m];
  // elementwise slice (once) -> outSnew + packed LDS
  #pragma unroll 4
  for (int l = 0; l < 64; ++l){
    int idx = l * 256 + t, r = idx >> 9, c = idx & 511;
    size_t g = ((size_t)(row0 + r) * 8 + m) * 512 + c;
    float pre = pA[g] + sc * pB[g] + bias[m * 512 + c];
    float sn = (1.f - lm) * Si[g] + lm * fast_tanh(pre);
    outSnew[g] = sn;
    ssh[PK(r, c, 512)] = f2b(sn);
  }
  __syncthreads();
  const short* A0 = ssh + rh * 8192 + fm * 8 + fq * 128;   // rows rh*16+fm, k fq*8
  #pragma unroll 1
  for (int cb = 0; cb < 8; ++cb){
    const int col0 = cb * 64 + ch * 32;
    const short* B0 = WoutT + (size_t)(col0 + fm) * 4096 + m * 512 + fq * 8;
    f32x4 zz = {0.f, 0.f, 0.f, 0.f};
    f32x4 acc[2] = {zz, zz};
    mm32_d4(A0, B0, 16 * 4096, 512, 32, 16, acc);
    #pragma unroll
    for (int j = 0; j < 2; ++j)
      #pragma unroll
      for (int r = 0; r < 4; ++r){
        int row = row0 + rh * 16 + fq * 4 + r;
        int col = col0 + j * 16 + fm;
        atomicAdd(&outYi[row * 512 + col], acc[j][r]);
      }
  }
}

// ---------------------------------------------------------------------------
extern "C" void kernel_launch(void* const* d_in, const int* in_sizes, int n_in,
                              void* d_out, int out_size, void* d_ws, size_t ws_size,
                              hipStream_t stream) {
  const float* Xi   = (const float*)d_in[0];
  const float* Si   = (const float*)d_in[1];
  const float* Wq   = (const float*)d_in[2];
  const float* Wk   = (const float*)d_in[3];
  const float* Wv   = (const float*)d_in[4];
  const float* Wout = (const float*)d_in[5];
  const float* W    = (const float*)d_in[6];
  const float* Win  = (const float*)d_in[7];
  const float* bias = (const float*)d_in[8];
  const float* sr   = (const float*)d_in[9];
  const float* lr   = (const float*)d_in[10];

  float* ws = (float*)d_ws;
  short* Xa    = (short*)(ws + 0);         // chain ping-pong (blocked-swz), 4 MB each
  short* Xb    = (short*)(ws + 2097152);
  short* WTpP  = (short*)(ws + 4194304);   // packed bf16 W^T per unit
  short* SiB   = (short*)(ws + 5242880);   // [8192][512] bf16 (b-major, qkv)
  short* XiB   = (short*)(ws + 7340032);   // [1024][512] bf16
  short* WqT   = (short*)(ws + 7602176);   // [m][16][512] bf16
  short* WkT   = (short*)(ws + 7634944);
  short* WvT   = (short*)(ws + 7667712);
  short* WinTP = (short*)(ws + 7700480);   // packed [m]{512 rows, K=128}
  short* WoutT = (short*)(ws + 7962624);   // [512][4096] bf16
  float* Qb    = ws + 9011200;             // [1024][128] fp32
  float* Kb    = ws + 9142272;             // [B,M,N,A] fp32
  float* Vb    = ws + 10190848;
  short* UiBuP = (short*)(ws + 11239424);  // packed [m]{1024 rows, K=128}
  float* norm2 = ws + 13860864;            // 72 used (zeroed 136)
  short* SiBuP = (short*)(ws + 13861376);  // packed [m]{1024 rows, K=512}
  float* pA    = ws + 15958528;            // [1024,8,512] fp32 accA
  float* pB    = ws + 20152832;            // [1024,8,512] fp32 accB
  float* n2tmp = ws + 24347136;            // [8][64] per-tile |W|^2 partials

  float* outYi   = (float*)d_out;            // [1024,512]
  float* outSnew = (float*)d_out + 524288;   // [1024,8,512]

  // ---- merged prep (zero + converts + transposes + W-prep), one launch ----
  k_prep_all<<<3992, 256, 0, stream>>>(Si, Xi, Wq, Wk, Wv, Win, Wout, W,
                                       SiB, SiBuP, XiB, WqT, WkT, WvT, WinTP, WoutT,
                                       Xa, WTpP, outYi, norm2, n2tmp);

  // ---- spectral radius chain + piggybacked qkv (1-4) / attn (5-6) / pre (7-8) ----
  for (int lev = 1; lev <= NLEV; ++lev){
    const short* Xr = (lev & 1) ? Xa : Xb;
    short* Xw       = (lev & 1) ? Xb : Xa;
    const int extraY = (lev <= 4) ? 17 : (lev <= 6 ? 128 : 64);
    k_lev<<<dim3(8, 32 + extraY), 256, 0, stream>>>(Xr, Xw, norm2, n2tmp, lev,
                                                    SiB, XiB, WqT, WkT, WvT, Kb, Vb, Qb, UiBuP,
                                                    SiBuP, WinTP, WTpP, pA, pB);
  }

  // ---- tail: merged finalize + Yi GEMM, 32-row partition (8,32) ----
  k_yi4<<<dim3(8, 32), 256, 0, stream>>>(pA, pB, norm2, n2tmp, sr, bias, lr, Si,
                                         WoutT, outSnew, outYi);
}